// Round 17
// baseline (1572.516 us; speedup 1.0000x reference)
//
#include <hip/hip_runtime.h>
#include <math.h>

typedef __bf16 bf16;
typedef __bf16 bf16x8 __attribute__((ext_vector_type(8)));
typedef float f32x4 __attribute__((ext_vector_type(4)));

#define B_ 2
#define S_ 2048
#define D_ 2048
#define H_ 16
#define FF_ 2048
#define E_ 8
#define T_ 4096
#define TH_ 65536
#define CAP_ 4096

#define MFMA_(a, b, c) __builtin_amdgcn_mfma_f32_16x16x32_bf16(a, b, c, 0, 0, 0)

// XOR swizzle, bf16 tiles (rows of 64 bf16 = 128B), 16B granules.
__device__ __forceinline__ int swz(int row, int byteoff) {
  return row * 128 + (byteoff ^ ((row & 7) << 4));
}
// XOR swizzle, fp32 tiles (rows of 64 f32 = 256B), 32B granules.
__device__ __forceinline__ int swzf(int row, int byteoff) {
  return row * 256 + (byteoff ^ ((row & 7) << 5));
}

// Async global->LDS 16B staging (no VGPR round-trip). HW semantics: LDS dest =
// wave-uniform base + lane*16; global source address is per-lane. We keep LDS
// linear per wave and pre-apply the XOR swizzle to the SOURCE granule (the
// swizzle is an involution), so LDS bytes are identical to the old ds_write
// path -> bit-identical fragments.
__device__ __forceinline__ void gload16(const void* g, void* l) {
  __builtin_amdgcn_global_load_lds((const __attribute__((address_space(1))) void*)g,
                                   (__attribute__((address_space(3))) void*)l, 16, 0, 0);
}

// 2-way bf16 split: x ~= h + m, 16-17 mantissa bits covered; residual ~2^-18|x|.
__device__ __forceinline__ void split2(float x, bf16& h, bf16& m) {
  h = (bf16)x;
  m = (bf16)(x - (float)h);
}

// Read 8 consecutive f32 from (swizzled) LDS, split into 2 bf16x8 planes.
__device__ __forceinline__ void frag_split(const char* p, int off, bf16x8& r0, bf16x8& r1) {
  f32x4 u = *(const f32x4*)(p + off);
  f32x4 v = *(const f32x4*)(p + off + 16);
#pragma unroll
  for (int j = 0; j < 4; j++) { bf16 a, b; split2(u[j], a, b); r0[j] = a; r1[j] = b; }
#pragma unroll
  for (int j = 0; j < 4; j++) { bf16 a, b; split2(v[j], a, b); r0[4 + j] = a; r1[4 + j] = b; }
}

// 3-product fp32-emulated dot: keeps {00,01,10}; error ~2^-18 relative.
__device__ __forceinline__ f32x4 dot3(bf16x8 a0, bf16x8 a1,
                                      bf16x8 b0, bf16x8 b1, f32x4 c) {
  c = MFMA_(a0, b0, c);
  c = MFMA_(a0, b1, c);
  c = MFMA_(a1, b0, c);
  return c;
}

__device__ __forceinline__ float blk_sum(float v, float* sbuf, int tid) {
#pragma unroll
  for (int mk = 32; mk; mk >>= 1) v += __shfl_xor(v, mk);
  __syncthreads();
  if ((tid & 63) == 0) sbuf[tid >> 6] = v;
  __syncthreads();
  return sbuf[0] + sbuf[1] + sbuf[2] + sbuf[3];
}

// fp32 [R][C] -> fp32 [C][R]
__global__ __launch_bounds__(256) void k_transpose32(const float* __restrict__ src,
                                                     float* __restrict__ dst, int R, int C) {
  __shared__ float tile[32][33];
  int tx = threadIdx.x, ty = threadIdx.y;
  int c0 = blockIdx.x * 32, r0 = blockIdx.y * 32;
#pragma unroll
  for (int j = 0; j < 32; j += 8) tile[ty + j][tx] = src[(size_t)(r0 + ty + j) * C + (c0 + tx)];
  __syncthreads();
#pragma unroll
  for (int j = 0; j < 32; j += 8)
    dst[(size_t)(c0 + ty + j) * R + (r0 + tx)] = tile[tx][ty + j];
}

// Batched fp32 [128][64] -> fp32 [64][128] x3 (z selects src; dst stride 8192 floats).
__global__ __launch_bounds__(256) void k_transpose32b3(const float* __restrict__ s0,
                                                       const float* __restrict__ s1x,
                                                       const float* __restrict__ s2,
                                                       float* __restrict__ dbase) {
  __shared__ float tile[32][33];
  int z = blockIdx.z;
  const float* src = z == 0 ? s0 : (z == 1 ? s1x : s2);
  float* dst = dbase + (size_t)z * 8192;
  int tx = threadIdx.x, ty = threadIdx.y;
  int c0 = blockIdx.x * 32, r0 = blockIdx.y * 32;
#pragma unroll
  for (int j = 0; j < 32; j += 8) tile[ty + j][tx] = src[(size_t)(r0 + ty + j) * 64 + (c0 + tx)];
  __syncthreads();
#pragma unroll
  for (int j = 0; j < 32; j += 8)
    dst[(size_t)(c0 + ty + j) * 128 + (r0 + tx)] = tile[tx][ty + j];
}

// Batched fp32 [2048][2048] -> bf16 [2048][2048]^T x3 (z selects src; dst stride 4194304).
__global__ __launch_bounds__(256) void k_transpose_sh3(const float* __restrict__ s0,
                                                       const float* __restrict__ s1x,
                                                       const float* __restrict__ s2,
                                                       bf16* __restrict__ dbase) {
  __shared__ float tile[32][33];
  int z = blockIdx.z;
  const float* src = z == 0 ? s0 : (z == 1 ? s1x : s2);
  bf16* dst = dbase + (size_t)z * 4194304;
  int tx = threadIdx.x, ty = threadIdx.y;
  int c0 = blockIdx.x * 32, r0 = blockIdx.y * 32;
#pragma unroll
  for (int j = 0; j < 32; j += 8) tile[ty + j][tx] = src[(size_t)(r0 + ty + j) * 2048 + (c0 + tx)];
  __syncthreads();
#pragma unroll
  for (int j = 0; j < 32; j += 8)
    dst[(size_t)(c0 + ty + j) * 2048 + (r0 + tx)] = (bf16)tile[tx][ty + j];
}

// Batched expert-weight transpose for mid phase, fp32 [2048][2048] -> bf16 ^T.
// z=(pair,mat) -> src = (mat? W3 : W1)[eBase + pair].
__global__ __launch_bounds__(256) void k_transpose_moe(const float* __restrict__ W1,
                                                       const float* __restrict__ W3,
                                                       bf16* __restrict__ dstB, int eBase) {
  __shared__ float tile[32][33];
  int tx = threadIdx.x, ty = threadIdx.y;
  int z = blockIdx.z;
  const float* src = ((z & 1) ? W3 : W1) + (size_t)(eBase + (z >> 1)) * 4194304;
  bf16* dst = dstB + (size_t)z * 4194304;
  int c0 = blockIdx.x * 32, r0 = blockIdx.y * 32;
#pragma unroll
  for (int j = 0; j < 32; j += 8) tile[ty + j][tx] = src[(size_t)(r0 + ty + j) * 2048 + (c0 + tx)];
  __syncthreads();
#pragma unroll
  for (int j = 0; j < 32; j += 8)
    dst[(size_t)(c0 + ty + j) * 2048 + (r0 + tx)] = (bf16)tile[tx][ty + j];
}

// Down-phase transpose: z<8 -> We2[z] into dstB[z]; z=8 -> Ws2 into dst2.
__global__ __launch_bounds__(256) void k_transpose_moe2(const float* __restrict__ We2,
                                                        const float* __restrict__ Ws2,
                                                        bf16* __restrict__ dstB,
                                                        bf16* __restrict__ dst2) {
  __shared__ float tile[32][33];
  int tx = threadIdx.x, ty = threadIdx.y;
  int z = blockIdx.z;
  const float* src = (z < 8) ? (We2 + (size_t)z * 4194304) : Ws2;
  bf16* dst = (z < 8) ? (dstB + (size_t)z * 4194304) : dst2;
  int c0 = blockIdx.x * 32, r0 = blockIdx.y * 32;
#pragma unroll
  for (int j = 0; j < 32; j += 8) tile[ty + j][tx] = src[(size_t)(r0 + ty + j) * 2048 + (c0 + tx)];
  __syncthreads();
#pragma unroll
  for (int j = 0; j < 32; j += 8)
    dst[(size_t)(c0 + ty + j) * 2048 + (r0 + tx)] = (bf16)tile[tx][ty + j];
}

// fp32 [R][C] -> two bf16 planes [C][R] (hi/lo split).
__global__ __launch_bounds__(256) void k_transpose_split(const float* __restrict__ src,
                                                         bf16* __restrict__ dh, bf16* __restrict__ dl,
                                                         int R, int C) {
  __shared__ float tile[32][33];
  int tx = threadIdx.x, ty = threadIdx.y;
  int c0 = blockIdx.x * 32, r0 = blockIdx.y * 32;
#pragma unroll
  for (int j = 0; j < 32; j += 8) tile[ty + j][tx] = src[(size_t)(r0 + ty + j) * C + (c0 + tx)];
  __syncthreads();
#pragma unroll
  for (int j = 0; j < 32; j += 8) {
    float v = tile[tx][ty + j];
    bf16 h, l;
    split2(v, h, l);
    size_t o = (size_t)(c0 + ty + j) * R + (r0 + tx);
    dh[o] = h;
    dl[o] = l;
  }
}

// Batched split-transpose for Wq/Wk/Wv (z selects src; dst stride 8388608 bf16 per plane pair).
__global__ __launch_bounds__(256) void k_transpose_split3(const float* __restrict__ s0,
                                                          const float* __restrict__ s1x,
                                                          const float* __restrict__ s2,
                                                          bf16* __restrict__ dbase) {
  __shared__ float tile[32][33];
  int z = blockIdx.z;
  const float* src = z == 0 ? s0 : (z == 1 ? s1x : s2);
  bf16* dh = dbase + (size_t)z * 8388608;
  bf16* dl = dh + 4194304;
  int tx = threadIdx.x, ty = threadIdx.y;
  int c0 = blockIdx.x * 32, r0 = blockIdx.y * 32;
#pragma unroll
  for (int j = 0; j < 32; j += 8) tile[ty + j][tx] = src[(size_t)(r0 + ty + j) * 2048 + (c0 + tx)];
  __syncthreads();
#pragma unroll
  for (int j = 0; j < 32; j += 8) {
    float v = tile[tx][ty + j];
    bf16 h, l;
    split2(v, h, l);
    size_t o = (size_t)(c0 + ty + j) * 2048 + (r0 + tx);
    dh[o] = h;
    dl[o] = l;
  }
}

// v_c fp32 [(b,s,h), r] -> vct bf16 planes [(b,h), r, s]
__global__ __launch_bounds__(256) void k_tr_v32s(const float* __restrict__ vc,
                                                 bf16* __restrict__ vh, bf16* __restrict__ vl) {
  __shared__ float tile[32][33];
  int tx = threadIdx.x, ty = threadIdx.y;
  int z = blockIdx.z;
  int s0 = blockIdx.x * 32, r0 = blockIdx.y * 32;
  int b = z >> 4, h = z & 15;
#pragma unroll
  for (int j = 0; j < 32; j += 8) {
    int s = s0 + ty + j;
    tile[ty + j][tx] = vc[((size_t)((b * S_ + s) * H_ + h)) * 64 + r0 + tx];
  }
  __syncthreads();
#pragma unroll
  for (int j = 0; j < 32; j += 8) {
    int r = r0 + ty + j;
    float v = tile[tx][ty + j];
    bf16 hh, ll;
    split2(v, hh, ll);
    size_t o = ((size_t)(z * 64 + r)) * S_ + s0 + tx;
    vh[o] = hh;
    vl[o] = ll;
  }
}

// LN -> split bf16 planes.
__global__ __launch_bounds__(256) void k_ln32_split(const float* __restrict__ x, const float* __restrict__ w,
                                                    const float* __restrict__ bb,
                                                    bf16* __restrict__ oh, bf16* __restrict__ ol) {
  __shared__ float sbuf[4];
  int row = blockIdx.x, tid = threadIdx.x;
  const float* xr = x + (size_t)row * D_;
  float v[8];
  float s = 0.f;
#pragma unroll
  for (int j = 0; j < 8; j++) { v[j] = xr[tid + 256 * j]; s += v[j]; }
  float mu = blk_sum(s, sbuf, tid) * (1.f / D_);
  float qs = 0.f;
#pragma unroll
  for (int j = 0; j < 8; j++) { float d = v[j] - mu; qs += d * d; }
  float rs = rsqrtf(blk_sum(qs, sbuf, tid) * (1.f / D_) + 1e-5f);
#pragma unroll
  for (int j = 0; j < 8; j++) {
    int c = tid + 256 * j;
    float xn = (v[j] - mu) * rs * w[c] + bb[c];
    bf16 h, l;
    split2(xn, h, l);
    oh[(size_t)row * D_ + c] = h;
    ol[(size_t)row * D_ + c] = l;
  }
}

// Plane GEMM (fp32-accurate via pre-split bf16 hi/lo planes, dot3).
// C[M,N] = (Ah+Al)[M,K] @ (Bh+Bl)[N,K]^T. EPI 0: fp32 store; 1: resid+store.
// Staging via global_load_lds (linear LDS dest, pre-swizzled source granule);
// LDS bytes identical to the old ds_write path -> bit-identical fragments.
template <int EPI>
__global__ __launch_bounds__(256) void k_gemm32s(const bf16* __restrict__ Ah, const bf16* __restrict__ Al, int lda,
                                                 const bf16* __restrict__ Bh, const bf16* __restrict__ Bl, int ldb,
                                                 float* __restrict__ C, int ldc,
                                                 int M, int N, int Kd,
                                                 const float* __restrict__ resid) {
  __shared__ __align__(16) char Ahs[16384];
  __shared__ __align__(16) char Als[16384];
  __shared__ __align__(16) char Bhs[16384];
  __shared__ __align__(16) char Bls[16384];
  int bm = blockIdx.y * 128, bn = blockIdx.x * 128;
  int tid = threadIdx.x;
  int srow = tid >> 3;
  int gsel = (((tid & 7) ^ ((tid >> 3) & 7))) * 8;  // pre-swizzled source granule (elements)
  int arow[4], brow[4];
#pragma unroll
  for (int i = 0; i < 4; i++) {
    int r = bm + srow + 32 * i;
    arow[i] = r < M ? r : (M - 1);
    int q = bn + srow + 32 * i;
    brow[i] = q < N ? q : (N - 1);
  }
  f32x4 acc[4][4] = {};
  int lane = tid & 63, w = tid >> 6, g = lane >> 4, lr = lane & 15;
  int wm = (w >> 1) * 64, wn = (w & 1) * 64;
  for (int kt = 0; kt < Kd; kt += 64) {
#pragma unroll
    for (int i = 0; i < 4; i++) {
      int lo = i * 4096 + w * 1024;  // wave-uniform linear dest
      gload16(Ah + (size_t)arow[i] * lda + kt + gsel, Ahs + lo);
      gload16(Al + (size_t)arow[i] * lda + kt + gsel, Als + lo);
      gload16(Bh + (size_t)brow[i] * ldb + kt + gsel, Bhs + lo);
      gload16(Bl + (size_t)brow[i] * ldb + kt + gsel, Bls + lo);
    }
    __syncthreads();
#pragma unroll
    for (int ks = 0; ks < 2; ks++) {
      bf16x8 ah[4], al[4], bh[4], bl[4];
#pragma unroll
      for (int m = 0; m < 4; m++) {
        ah[m] = *(const bf16x8*)(Ahs + swz(wm + m * 16 + lr, ks * 64 + g * 16));
        al[m] = *(const bf16x8*)(Als + swz(wm + m * 16 + lr, ks * 64 + g * 16));
      }
#pragma unroll
      for (int n = 0; n < 4; n++) {
        bh[n] = *(const bf16x8*)(Bhs + swz(wn + n * 16 + lr, ks * 64 + g * 16));
        bl[n] = *(const bf16x8*)(Bls + swz(wn + n * 16 + lr, ks * 64 + g * 16));
      }
#pragma unroll
      for (int m = 0; m < 4; m++)
#pragma unroll
        for (int n = 0; n < 4; n++)
          acc[m][n] = dot3(ah[m], al[m], bh[n], bl[n], acc[m][n]);
    }
    __syncthreads();
  }
#pragma unroll
  for (int m = 0; m < 4; m++)
#pragma unroll
    for (int n = 0; n < 4; n++)
#pragma unroll
      for (int r = 0; r < 4; r++) {
        int row = bm + wm + m * 16 + g * 4 + r;
        int col = bn + wn + n * 16 + lr;
        if (row < M && col < N) {
          float val = acc[m][n][r];
          if (EPI == 1) val += resid[(size_t)row * ldc + col];
          C[(size_t)row * ldc + col] = val;
        }
      }
}

// Fused QKV plane GEMM: z selects B-plane pair (stride 8388608 bf16) and C (stride 8388608 f32).
// M=4096, N=2048, K=2048 fixed; same per-output MFMA order as k_gemm32s<0>.
// global_load_lds staging (bit-identical LDS bytes).
__global__ __launch_bounds__(256) void k_gemm32s_qkv(const bf16* __restrict__ Ah, const bf16* __restrict__ Al,
                                                     const bf16* __restrict__ Bhb,
                                                     float* __restrict__ Cb) {
  int z = blockIdx.z;
  const bf16* Bh = Bhb + (size_t)z * 8388608;
  const bf16* Bl = Bh + 4194304;
  float* C = Cb + (size_t)z * 8388608;
  __shared__ __align__(16) char Ahs[16384];
  __shared__ __align__(16) char Als[16384];
  __shared__ __align__(16) char Bhs[16384];
  __shared__ __align__(16) char Bls[16384];
  int bm = blockIdx.y * 128, bn = blockIdx.x * 128;
  int tid = threadIdx.x;
  int srow = tid >> 3;
  int gsel = (((tid & 7) ^ ((tid >> 3) & 7))) * 8;
  f32x4 acc[4][4] = {};
  int lane = tid & 63, w = tid >> 6, g = lane >> 4, lr = lane & 15;
  int wm = (w >> 1) * 64, wn = (w & 1) * 64;
  for (int kt = 0; kt < 2048; kt += 64) {
#pragma unroll
    for (int i = 0; i < 4; i++) {
      int row = srow + 32 * i;
      int lo = i * 4096 + w * 1024;
      gload16(Ah + (size_t)(bm + row) * 2048 + kt + gsel, Ahs + lo);
      gload16(Al + (size_t)(bm + row) * 2048 + kt + gsel, Als + lo);
      gload16(Bh + (size_t)(bn + row) * 2048 + kt + gsel, Bhs + lo);
      gload16(Bl + (size_t)(bn + row) * 2048 + kt + gsel, Bls + lo);
    }
    __syncthreads();
#pragma unroll
    for (int ks = 0; ks < 2; ks++) {
      bf16x8 ah[4], al[4], bh[4], bl[4];
#pragma unroll
      for (int m = 0; m < 4; m++) {
        ah[m] = *(const bf16x8*)(Ahs + swz(wm + m * 16 + lr, ks * 64 + g * 16));
        al[m] = *(const bf16x8*)(Als + swz(wm + m * 16 + lr, ks * 64 + g * 16));
      }
#pragma unroll
      for (int n = 0; n < 4; n++) {
        bh[n] = *(const bf16x8*)(Bhs + swz(wn + n * 16 + lr, ks * 64 + g * 16));
        bl[n] = *(const bf16x8*)(Bls + swz(wn + n * 16 + lr, ks * 64 + g * 16));
      }
#pragma unroll
      for (int m = 0; m < 4; m++)
#pragma unroll
        for (int n = 0; n < 4; n++)
          acc[m][n] = dot3(ah[m], al[m], bh[n], bl[n], acc[m][n]);
    }
    __syncthreads();
  }
#pragma unroll
  for (int m = 0; m < 4; m++)
#pragma unroll
    for (int n = 0; n < 4; n++)
#pragma unroll
      for (int r = 0; r < 4; r++) {
        int row = bm + wm + m * 16 + g * 4 + r;
        int col = bn + wn + n * 16 + lr;
        C[(size_t)row * 2048 + col] = acc[m][n][r];
      }
}

// fp32-in GEMM with in-kernel split. EPI 0: fp32 store.
// EPI 3: fused silu-gate epilogue: gated = silu(Cin[idx]) * acc, split-stored
// to Ch/Cl (Cin = qgate passed via the C pointer, read-only).
// Staging via global_load_lds with pre-swizzled fp32 source granule.
template <int EPI>
__global__ __launch_bounds__(256) void k_gemm32(const float* __restrict__ A, int lda,
                                                const float* __restrict__ Bt, int ldb,
                                                float* __restrict__ C, int ldc,
                                                int M, int N, int Kd,
                                                bf16* __restrict__ Ch, bf16* __restrict__ Cl) {
  __shared__ __align__(16) char As[32768];
  __shared__ __align__(16) char Bs[32768];
  int bm = blockIdx.y * 128, bn = blockIdx.x * 128;
  int tid = threadIdx.x;
  int g16 = tid & 15;
  int rquot = tid >> 4;  // row base per pass (0..15)
  int gsrcf = (((g16 >> 1) ^ (rquot & 7)) * 8) + ((g16 & 1) * 4);  // source float offset
  f32x4 acc[4][4] = {};
  int lane = tid & 63, w = tid >> 6, g = lane >> 4, lr = lane & 15;
  int wm = (w >> 1) * 64, wn = (w & 1) * 64;
  for (int kt = 0; kt < Kd; kt += 64) {
#pragma unroll
    for (int i = 0; i < 8; i++) {
      int rloc = rquot + 16 * i;
      int ra = bm + rloc; ra = ra < M ? ra : (M - 1);
      int rb = bn + rloc; rb = rb < N ? rb : (N - 1);
      int lo = i * 4096 + w * 1024;
      gload16(A + (size_t)ra * lda + kt + gsrcf, As + lo);
      gload16(Bt + (size_t)rb * ldb + kt + gsrcf, Bs + lo);
    }
    __syncthreads();
#pragma unroll
    for (int ks = 0; ks < 2; ks++) {
      bf16x8 a0[4], a1[4], b0[4], b1[4];
#pragma unroll
      for (int m = 0; m < 4; m++)
        frag_split(As, swzf(wm + m * 16 + lr, ks * 128 + g * 32), a0[m], a1[m]);
#pragma unroll
      for (int n = 0; n < 4; n++)
        frag_split(Bs, swzf(wn + n * 16 + lr, ks * 128 + g * 32), b0[n], b1[n]);
#pragma unroll
      for (int m = 0; m < 4; m++)
#pragma unroll
        for (int n = 0; n < 4; n++)
          acc[m][n] = dot3(a0[m], a1[m], b0[n], b1[n], acc[m][n]);
    }
    __syncthreads();
  }
#pragma unroll
  for (int m = 0; m < 4; m++)
#pragma unroll
    for (int n = 0; n < 4; n++)
#pragma unroll
      for (int r = 0; r < 4; r++) {
        int row = bm + wm + m * 16 + g * 4 + r;
        int col = bn + wn + n * 16 + lr;
        if (row < M && col < N) {
          if (EPI == 3) {
            float up = acc[m][n][r];
            float x = C[(size_t)row * ldc + col];
            float gg = x / (1.f + expf(-x)) * up;
            bf16 h, l;
            split2(gg, h, l);
            Ch[(size_t)row * ldc + col] = h;
            Cl[(size_t)row * ldc + col] = l;
          } else {
            C[(size_t)row * ldc + col] = acc[m][n][r];
          }
        }
      }
}

// Fused per-head projections, 128x64 tile (48KB LDS): z=0 q_a (plane out),
// z=1 k_c (plane out), z=2 v_c (fp32 out). A stride 8388608 f32; B stride 8192 f32;
// plane-out stride 8388608 bf16. global_load_lds staging (bit-identical bytes).
__global__ __launch_bounds__(256) void k_projn64(const float* __restrict__ Ab,
                                                 const float* __restrict__ Btb,
                                                 bf16* __restrict__ Pb,
                                                 float* __restrict__ Vb) {
  int z = blockIdx.z;
  const float* A = Ab + (size_t)z * 8388608;
  const float* Bt = Btb + (size_t)z * 8192;
  __shared__ __align__(16) char As[32768];
  __shared__ __align__(16) char Bs[16384];
  int bm = blockIdx.y * 128;
  int tid = threadIdx.x;
  int lane = tid & 63, w = tid >> 6, g = lane >> 4, lr = lane & 15;
  int g16 = tid & 15;
  int rquot = tid >> 4;
  int gsrcf = (((g16 >> 1) ^ (rquot & 7)) * 8) + ((g16 & 1) * 4);
  f32x4 acc[2][4] = {};
  for (int kt = 0; kt < 128; kt += 64) {
#pragma unroll
    for (int i = 0; i < 8; i++) {
      int rloc = rquot + 16 * i;
      int lo = i * 4096 + w * 1024;
      gload16(A + (size_t)(bm + rloc) * 128 + kt + gsrcf, As + lo);
    }
#pragma unroll
    for (int i = 0; i < 4; i++) {
      int rloc = rquot + 16 * i;
      int lo = i * 4096 + w * 1024;
      gload16(Bt + (size_t)rloc * 128 + kt + gsrcf, Bs + lo);
    }
    __syncthreads();
#pragma unroll
    for (int ks = 0; ks < 2; ks++) {
      bf16x8 a0[2], a1[2], b0[4], b1[4];
#pragma unroll
      for (int m = 0; m < 2; m++)
        frag_split(As, swzf(w * 32 + m * 16 + lr, ks * 128 + g * 32), a0[m], a1[m]);
#pragma unroll
      for (int n = 0; n < 4; n++)
        frag_split(Bs, swzf(n * 16 + lr, ks * 128 + g * 32), b0[n], b1[n]);
#pragma unroll
      for (int m = 0; m < 2; m++)
#pragma unroll
        for (int n = 0; n < 4; n++)
          acc[m][n] = dot3(a0[m], a1[m], b0[n], b1[n], acc[m][n]);
    }
    __syncthreads();
  }
  bf16* Ph = Pb + (size_t)z * 8388608;
  bf16* Pl = Ph + 4194304;
#pragma unroll
  for (int m = 0; m < 2; m++)
#pragma unroll
    for (int n = 0; n < 4; n++)
#pragma unroll
      for (int r = 0; r < 4; r++) {
        int row = bm + w * 32 + m * 16 + g * 4 + r;
        int col = n * 16 + lr;
        size_t o = (size_t)row * 64 + col;
        float val = acc[m][n][r];
        if (z == 2) {
          Vb[o] = val;
        } else {
          bf16 h, l;
          split2(val, h, l);
          Ph[o] = h;
          Pl[o] = l;
        }
      }
}

__global__ __launch_bounds__(256) void k_rope32(float* __restrict__ q, float* __restrict__ k) {
  int idx = blockIdx.x * 256 + threadIdx.x;  // TH_*32 threads
  int i = idx & 31, rowth = idx >> 5;
  int s = (rowth >> 4) & (S_ - 1);
  size_t base = (size_t)rowth * 128;
  float freq = expf(-0.28782313662425576f * (float)i);  // ln(10000)/32
  float ang = (float)s * freq;
  float sn, cs;
  sincosf(ang, &sn, &cs);
  float q1 = q[base + i], q2 = q[base + i + 32];
  q[base + i] = q1 * cs - q2 * sn;
  q[base + i + 32] = q2 * cs + q1 * sn;
  float k1 = k[base + i], k2 = k[base + i + 32];
  k[base + i] = k1 * cs - k2 * sn;
  k[base + i + 32] = k2 * cs + k1 * sn;
}

// Flash attention, fp32-accurate via pre-split bf16 hi/lo planes for Q,K,V.
// R13-exact (best-known config): two-plane P, dot3 PV, 64KB LDS, expf,
// ds_write-staged K/V (attn is barrier-bound; gload_lds staging was neutral).
// XCD-aware (qt,bh) remap (mapping-only).
// NOTE: attention values feed the MoE router's top-2 selection; any numeric
// perturbation here flips borderline tokens' expert choice (absmax ~1.2).
// Do not change the math in this kernel.
__global__ __launch_bounds__(256) void k_attn32p(const bf16* __restrict__ qh, const bf16* __restrict__ ql,
                                                 const bf16* __restrict__ kh, const bf16* __restrict__ kl,
                                                 const bf16* __restrict__ vh, const bf16* __restrict__ vl,
                                                 float* __restrict__ attc) {
  __shared__ __align__(16) char L[65536];
  int lin = blockIdx.x + 16 * blockIdx.y;
  int xcd = lin & 7, j = lin >> 3;
  int bh = xcd * 4 + (j & 3);
  int qt = j >> 2;
  int b = bh >> 4, h = bh & 15;
  int tid = threadIdx.x, lane = tid & 63, w = tid >> 6, g = lane >> 4, lr = lane & 15;
  int s0 = qt * 128;
  int srow = tid >> 3, scol = (tid & 7) * 8;
  char* Qsh = L;
  char* Qsl = L + 16384;
#pragma unroll
  for (int i = 0; i < 4; i++) {
    int row = srow + 32 * i;
    size_t goff = ((size_t)((b * S_ + s0 + row) * H_ + h)) * 64 + scol;
    int o = swz(row, scol * 2);
    *(uint4*)(Qsh + o) = *(const uint4*)(qh + goff);
    *(uint4*)(Qsl + o) = *(const uint4*)(ql + goff);
  }
  __syncthreads();
  bf16x8 qf0[2][2], qf1[2][2];
#pragma unroll
  for (int m = 0; m < 2; m++)
#pragma unroll
    for (int ks = 0; ks < 2; ks++) {
      qf0[m][ks] = *(const bf16x8*)(Qsh + swz(w * 32 + m * 16 + lr, ks * 64 + g * 16));
      qf1[m][ks] = *(const bf16x8*)(Qsl + swz(w * 32 + m * 16 + lr, ks * 64 + g * 16));
    }
  __syncthreads();  // all waves done reading Q before K/V overwrite
  char* Ksh = L;
  char* Ksl = L + 8192;
  char* Vsh = L + 16384;
  char* Vsl = L + 24576;
  char* Ph = L + 32768 + w * 8192;
  char* Pl = Ph + 4096;
  f32x4 acc[2][4] = {};
  float mrun[2][4], lrun[2][4];
#pragma unroll
  for (int m = 0; m < 2; m++)
#pragma unroll
    for (int r = 0; r < 4; r++) { mrun[m][r] = -1e30f; lrun[m][r] = 0.f; }
  for (int kt = 0; kt < S_; kt += 64) {
#pragma unroll
    for (int i = 0; i < 2; i++) {
      int rr = srow + 32 * i;
      size_t koff = ((size_t)((b * S_ + kt + rr) * H_ + h)) * 64 + scol;
      size_t voff = ((size_t)(bh * 64 + rr)) * S_ + kt + scol;
      int o = swz(rr, scol * 2);
      *(uint4*)(Ksh + o) = *(const uint4*)(kh + koff);
      *(uint4*)(Ksl + o) = *(const uint4*)(kl + koff);
      *(uint4*)(Vsh + o) = *(const uint4*)(vh + voff);
      *(uint4*)(Vsl + o) = *(const uint4*)(vl + voff);
    }
    __syncthreads();
    f32x4 sc[2][4] = {};
#pragma unroll
    for (int ks = 0; ks < 2; ks++) {
      bf16x8 k0[4], k1[4];
#pragma unroll
      for (int n = 0; n < 4; n++) {
        k0[n] = *(const bf16x8*)(Ksh + swz(n * 16 + lr, ks * 64 + g * 16));
        k1[n] = *(const bf16x8*)(Ksl + swz(n * 16 + lr, ks * 64 + g * 16));
      }
      __builtin_amdgcn_s_setprio(1);
#pragma unroll
      for (int m = 0; m < 2; m++)
#pragma unroll
        for (int n = 0; n < 4; n++)
          sc[m][n] = dot3(qf0[m][ks], qf1[m][ks], k0[n], k1[n], sc[m][n]);
      __builtin_amdgcn_s_setprio(0);
    }
#pragma unroll
    for (int m = 0; m < 2; m++)
#pragma unroll
      for (int r = 0; r < 4; r++) {
        float a0 = sc[m][0][r] * 0.125f, a1 = sc[m][1][r] * 0.125f;
        float a2 = sc[m][2][r] * 0.125f, a3 = sc[m][3][r] * 0.125f;
        float mx = fmaxf(fmaxf(a0, a1), fmaxf(a2, a3));
#pragma unroll
        for (int mk = 1; mk < 16; mk <<= 1) mx = fmaxf(mx, __shfl_xor(mx, mk));
        float mo = mrun[m][r];
        float mn = fmaxf(mo, mx);
        float f = expf(mo - mn);
        float p0 = expf(a0 - mn), p1 = expf(a1 - mn), p2 = expf(a2 - mn), p3 = expf(a3 - mn);
        int prow = m * 16 + g * 4 + r;
        bf16 h0, l0, h1, l1, h2, l2, h3, l3;
        split2(p0, h0, l0);
        split2(p1, h1, l1);
        split2(p2, h2, l2);
        split2(p3, h3, l3);
        *(bf16*)(Ph + swz(prow, lr * 2)) = h0;
        *(bf16*)(Pl + swz(prow, lr * 2)) = l0;
        *(bf16*)(Ph + swz(prow, 32 + lr * 2)) = h1;
        *(bf16*)(Pl + swz(prow, 32 + lr * 2)) = l1;
        *(bf16*)(Ph + swz(prow, 64 + lr * 2)) = h2;
        *(bf16*)(Pl + swz(prow, 64 + lr * 2)) = l2;
        *(bf16*)(Ph + swz(prow, 96 + lr * 2)) = h3;
        *(bf16*)(Pl + swz(prow, 96 + lr * 2)) = l3;
        float ps = p0 + p1 + p2 + p3;
#pragma unroll
        for (int mk = 1; mk < 16; mk <<= 1) ps += __shfl_xor(ps, mk);
        lrun[m][r] = lrun[m][r] * f + ps;
        mrun[m][r] = mn;
#pragma unroll
        for (int n = 0; n < 4; n++) acc[m][n][r] *= f;
      }
#pragma unroll
    for (int ks = 0; ks < 2; ks++) {
      bf16x8 p0f[2], p1f[2], v0f[4], v1f[4];
#pragma unroll
      for (int m = 0; m < 2; m++) {
        p0f[m] = *(const bf16x8*)(Ph + swz(m * 16 + lr, ks * 64 + g * 16));
        p1f[m] = *(const bf16x8*)(Pl + swz(m * 16 + lr, ks * 64 + g * 16));
      }
#pragma unroll
      for (int n = 0; n < 4; n++) {
        v0f[n] = *(const bf16x8*)(Vsh + swz(n * 16 + lr, ks * 64 + g * 16));
        v1f[n] = *(const bf16x8*)(Vsl + swz(n * 16 + lr, ks * 64 + g * 16));
      }
      __builtin_amdgcn_s_setprio(1);
#pragma unroll
      for (int m = 0; m < 2; m++)
#pragma unroll
        for (int n = 0; n < 4; n++)
          acc[m][n] = dot3(p0f[m], p1f[m], v0f[n], v1f[n], acc[m][n]);
      __builtin_amdgcn_s_setprio(0);
    }
    __syncthreads();
  }
#pragma unroll
  for (int m = 0; m < 2; m++)
#pragma unroll
    for (int n = 0; n < 4; n++)
#pragma unroll
      for (int r = 0; r < 4; r++) {
        int s = s0 + w * 32 + m * 16 + g * 4 + r;
        attc[((size_t)((b * S_ + s) * H_ + h)) * 64 + n * 16 + lr] = acc[m][n][r] / lrun[m][r];
      }
}

// LN2 (fp32) + router logits (fp32) + top-2 + list append; writes xf bf16.
__global__ __launch_bounds__(256) void k_router(const float* __restrict__ hbuf,
                                                const float* __restrict__ w2, const float* __restrict__ b2,
                                                const float* __restrict__ Wg, bf16* __restrict__ xf,
                                                int* __restrict__ count, int* __restrict__ permg,
                                                int* __restrict__ permt, float* __restrict__ wslot) {
  __shared__ float sbuf[4];
  int t = blockIdx.x, tid = threadIdx.x;
  const float* hr = hbuf + (size_t)t * D_;
  float v[8];
  float s = 0.f;
#pragma unroll
  for (int j = 0; j < 8; j++) { v[j] = hr[tid + 256 * j]; s += v[j]; }
  float mu = blk_sum(s, sbuf, tid) * (1.f / D_);
  float qs = 0.f;
#pragma unroll
  for (int j = 0; j < 8; j++) { float d = v[j] - mu; qs += d * d; }
  float rs = rsqrtf(blk_sum(qs, sbuf, tid) * (1.f / D_) + 1e-5f);
  float le[8] = {0, 0, 0, 0, 0, 0, 0, 0};
#pragma unroll
  for (int j = 0; j < 8; j++) {
    int c = tid + 256 * j;
    float xn = (v[j] - mu) * rs * w2[c] + b2[c];
    xf[(size_t)t * D_ + c] = (bf16)xn;
    const float* wr = Wg + (size_t)c * 8;
#pragma unroll
    for (int e = 0; e < 8; e++) le[e] += xn * wr[e];
  }
#pragma unroll
  for (int e = 0; e < 8; e++) le[e] = blk_sum(le[e], sbuf, tid);
  if (tid == 0) {
    float mx = le[0];
    for (int e = 1; e < 8; e++) mx = fmaxf(mx, le[e]);
    float p[8], sum = 0.f;
    for (int e = 0; e < 8; e++) { p[e] = expf(le[e] - mx); sum += p[e]; }
    int i0 = 0;
    for (int e = 1; e < 8; e++) if (p[e] > p[i0]) i0 = e;
    int i1 = (i0 == 0) ? 1 : 0;
    for (int e = 0; e < 8; e++) if (e != i0 && p[e] > p[i1]) i1 = e;
    float inv = 1.f / (p[i0] + p[i1]);
    int pos0 = atomicAdd(&count[i0], 1);
    permg[i0 * CAP_ + pos0] = 2 * t;
    permt[i0 * CAP_ + pos0] = t;
    int pos1 = atomicAdd(&count[i1], 1);
    permg[i1 * CAP_ + pos1] = 2 * t + 1;
    permt[i1 * CAP_ + pos1] = t;
    wslot[2 * t] = p[i0] * inv;
    wslot[2 * t + 1] = p[i1] * inv;
  }
}

// Shared-expert up projections fused, z=2: C_z = xf @ Bt_z^T (bf16, no gather).
__global__ __launch_bounds__(256) void k_gemm_sh(const bf16* __restrict__ A,
                                                 const bf16* __restrict__ Bt0, const bf16* __restrict__ Bt1,
                                                 bf16* __restrict__ C0, bf16* __restrict__ C1) {
  int z = blockIdx.z;
  const bf16* Bt = z ? Bt1 : Bt0;
  bf16* C = z ? C1 : C0;
  __shared__ __align__(16) char As[16384];
  __shared__ __align__(16) char Bs[16384];
  int bm = blockIdx.y * 128, bn = blockIdx.x * 128;
  int tid = threadIdx.x;
  int srow = tid >> 3;
  int gsel = (((tid & 7) ^ ((tid >> 3) & 7))) * 8;
  f32x4 acc[4][4] = {};
  int lane = tid & 63, w = tid >> 6, g = lane >> 4, lr = lane & 15;
  int wm = (w >> 1) * 64, wn = (w & 1) * 64;
  for (int kt = 0; kt < 2048; kt += 64) {
#pragma unroll
    for (int i = 0; i < 4; i++) {
      int row = srow + 32 * i;
      int lo = i * 4096 + w * 1024;
      gload16(A + (size_t)(bm + row) * 2048 + kt + gsel, As + lo);
      gload16(Bt + (size_t)(bn + row) * 2048 + kt + gsel, Bs + lo);
    }
    __syncthreads();
#pragma unroll
    for (int ks = 0; ks < 2; ks++) {
      bf16x8 af[4], bfr[4];
#pragma unroll
      for (int m = 0; m < 4; m++) af[m] = *(const bf16x8*)(As + swz(wm + m * 16 + lr, ks * 64 + g * 16));
#pragma unroll
      for (int n = 0; n < 4; n++) bfr[n] = *(const bf16x8*)(Bs + swz(wn + n * 16 + lr, ks * 64 + g * 16));
#pragma unroll
      for (int m = 0; m < 4; m++)
#pragma unroll
        for (int n = 0; n < 4; n++)
          acc[m][n] = MFMA_(af[m], bfr[n], acc[m][n]);
    }
    __syncthreads();
  }
#pragma unroll
  for (int m = 0; m < 4; m++)
#pragma unroll
    for (int n = 0; n < 4; n++)
#pragma unroll
      for (int r = 0; r < 4; r++) {
        int row = bm + wm + m * 16 + g * 4 + r;
        int col = bn + wn + n * 16 + lr;
        C[(size_t)row * 2048 + col] = (bf16)acc[m][n][r];
      }
}

// Fused routed-expert mid GEMM: z=(pair,mat); e=eBase+(z>>1); gather=permt[e],
// scatter=permg[e]; Bt = wteB[z]; C = mat? C1 : C0. global_load_lds staging.
__global__ __launch_bounds__(256) void k_gemm_moe(const bf16* __restrict__ A, int lda,
                                                  const bf16* __restrict__ wteB,
                                                  bf16* __restrict__ C0, bf16* __restrict__ C1, int ldc,
                                                  int N, int Kd,
                                                  const int* __restrict__ permt, const int* __restrict__ permg,
                                                  const int* __restrict__ count, int eBase) {
  int z = blockIdx.z;
  int e = eBase + (z >> 1);
  const int* amap = permt + e * CAP_;
  const int* cmap = permg + e * CAP_;
  bf16* C = (z & 1) ? C1 : C0;
  const bf16* Bt = wteB + (size_t)z * 4194304;
  int Mz = count[e];
  int bm = blockIdx.y * 128, bn = blockIdx.x * 128;
  if (bm >= Mz) return;
  __shared__ __align__(16) char As[16384];
  __shared__ __align__(16) char Bs[16384];
  int tid = threadIdx.x;
  int srow = tid >> 3;
  int gsel = (((tid & 7) ^ ((tid >> 3) & 7))) * 8;
  int arow[4], brow[4];
#pragma unroll
  for (int i = 0; i < 4; i++) {
    int r = bm + srow + 32 * i;
    int rc = r < Mz ? r : (Mz - 1);
    arow[i] = amap[rc];
    int bq = bn + srow + 32 * i;
    brow[i] = bq < N ? bq : (N - 1);
  }
  f32x4 acc[4][4] = {};
  int lane = tid & 63, w = tid >> 6, g = lane >> 4, lr = lane & 15;
  int wm = (w >> 1) * 64, wn = (w & 1) * 64;
  for (int kt = 0; kt < Kd; kt += 64) {
#pragma unroll
    for (int i = 0; i < 4; i++) {
      int lo = i * 4096 + w * 1024;
      gload16(A + (size_t)arow[i] * lda + kt + gsel, As + lo);
      gload16(Bt + (size_t)brow[i] * 2048 + kt + gsel, Bs + lo);
    }
    __syncthreads();
#pragma unroll
    for (int ks = 0; ks < 2; ks++) {
      bf16x8 af[4], bfr[4];
#pragma unroll
      for (int m = 0; m < 4; m++) af[m] = *(const bf16x8*)(As + swz(wm + m * 16 + lr, ks * 64 + g * 16));
#pragma unroll
      for (int n = 0; n < 4; n++) bfr[n] = *(const bf16x8*)(Bs + swz(wn + n * 16 + lr, ks * 64 + g * 16));
#pragma unroll
      for (int m = 0; m < 4; m++)
#pragma unroll
        for (int n = 0; n < 4; n++)
          acc[m][n] = MFMA_(af[m], bfr[n], acc[m][n]);
    }
    __syncthreads();
  }
#pragma unroll
  for (int m = 0; m < 4; m++)
#pragma unroll
    for (int n = 0; n < 4; n++)
#pragma unroll
      for (int r = 0; r < 4; r++) {
        int row = bm + wm + m * 16 + g * 4 + r;
        int col = bn + wn + n * 16 + lr;
        if (row < Mz && col < N) {
          C[(size_t)cmap[row] * ldc + col] = (bf16)acc[m][n][r];
        }
      }
}

// Down-projection mega GEMM, z in [0,9):
//   z<8: expert z: A=Amoe gather/scatter permg[z]; Bt=wteB[z]; C=Ce; M=count[z].
//   z=8: shared: A=Ash (smid); Bt=wts2t; C=Cs; M=T_; identity maps.
// global_load_lds staging; per-output math identical to the separate launches.
__global__ __launch_bounds__(256) void k_gemm_moe_dn(const bf16* __restrict__ Amoe,
                                                     const bf16* __restrict__ Ash,
                                                     const bf16* __restrict__ wteB,
                                                     const bf16* __restrict__ wts2t,
                                                     bf16* __restrict__ Ce, bf16* __restrict__ Cs,
                                                     const int* __restrict__ permg,
                                                     const int* __restrict__ count) {
  int z = blockIdx.z;
  const bf16* A;
  const bf16* Bt;
  bf16* C;
  const int* map = nullptr;
  int Mz;
  if (z < 8) {
    A = Amoe;
    Bt = wteB + (size_t)z * 4194304;
    C = Ce;
    map = permg + z * CAP_;
    Mz = count[z];
  } else {
    A = Ash;
    Bt = wts2t;
    C = Cs;
    Mz = T_;
  }
  int bm = blockIdx.y * 128, bn = blockIdx.x * 128;
  if (bm >= Mz) return;
  __shared__ __align__(16) char As[16384];
  __shared__ __align__(16) char Bs[16384];
  int tid = threadIdx.x;
  int srow = tid >> 3;
  int gsel = (((tid & 7) ^ ((tid >> 3) & 7))) * 8;
  int arow[4], brow[4];
#pragma unroll
  for (int i = 0; i < 4; i++) {
    int r = bm + srow + 32 * i;
    int rc = r < Mz ? r : (Mz - 1);
    arow[i] = map ? map[rc] : rc;
    brow[i] = bn + srow + 32 * i;
  }
  f32x4 acc[4][4] = {};
  int lane = tid & 63, w = tid >> 6, g = lane >> 4, lr = lane & 15;
  int wm = (w >> 1) * 64, wn = (w & 1) * 64;
  for (int kt = 0; kt < 2048; kt += 64) {
#pragma unroll
    for (int i = 0; i < 4; i++) {
      int lo = i * 4096 + w * 1024;
      gload16(A + (size_t)arow[i] * 2048 + kt + gsel, As + lo);
      gload16(Bt + (size_t)brow[i] * 2048 + kt + gsel, Bs + lo);
    }
    __syncthreads();
#pragma unroll
    for (int ks = 0; ks < 2; ks++) {
      bf16x8 af[4], bfr[4];
#pragma unroll
      for (int m = 0; m < 4; m++) af[m] = *(const bf16x8*)(As + swz(wm + m * 16 + lr, ks * 64 + g * 16));
#pragma unroll
      for (int n = 0; n < 4; n++) bfr[n] = *(const bf16x8*)(Bs + swz(wn + n * 16 + lr, ks * 64 + g * 16));
#pragma unroll
      for (int m = 0; m < 4; m++)
#pragma unroll
        for (int n = 0; n < 4; n++)
          acc[m][n] = MFMA_(af[m], bfr[n], acc[m][n]);
    }
    __syncthreads();
  }
#pragma unroll
  for (int m = 0; m < 4; m++)
#pragma unroll
    for (int n = 0; n < 4; n++)
#pragma unroll
      for (int r = 0; r < 4; r++) {
        int row = bm + wm + m * 16 + g * 4 + r;
        int col = bn + wn + n * 16 + lr;
        if (row < Mz) {
          size_t orow = map ? (size_t)map[row] : (size_t)row;
          C[orow * 2048 + col] = (bf16)acc[m][n][r];
        }
      }
}

__global__ __launch_bounds__(256) void k_silu_mul(const bf16* __restrict__ a, const bf16* __restrict__ b,
                                                  bf16* __restrict__ c, long n) {
  long i = ((long)blockIdx.x * 256 + threadIdx.x) * 8;
  if (i >= n) return;
  bf16x8 av = *(const bf16x8*)(a + i);
  bf16x8 bv = *(const bf16x8*)(b + i);
  bf16x8 cv;
#pragma unroll
  for (int j = 0; j < 8; j++) {
    float x = (float)av[j];
    float y = (float)bv[j];
    cv[j] = (bf16)(x / (1.f + expf(-x)) * y);
  }
  *(bf16x8*)(c + i) = cv;
}

__global__ __launch_bounds__(256) void k_combine(const float* __restrict__ hbuf, const bf16* __restrict__ shr,
                                                 const bf16* __restrict__ eout, const float* __restrict__ wslot,
                                                 float* __restrict__ out) {
  long i = ((long)blockIdx.x * 256 + threadIdx.x) * 4;
  int t = (int)(i >> 11);
  int c = (int)(i & (D_ - 1));
  float w0 = wslot[2 * t], w1 = wslot[2 * t + 1];
  float4 hv = *(const float4*)(hbuf + i);
  const bf16* s4 = shr + i;
  const bf16* e0 = eout + ((size_t)(2 * t)) * D_ + c;
  const bf16* e1 = e0 + D_;
  float4 o;
  o.x = hv.x + (float)s4[0] + w0 * (float)e0[0] + w1 * (float)e1[0];
  o.y = hv.y + (float)s4[1] + w0 * (float)e0[1] + w1 * (float)e1[1];
  o.z = hv.z + (float)s4[2] + w0 * (float)e0[2] + w1 * (float)e1[2];
  o.w = hv.w + (float)s4[3] + w0 * (float)e0[3] + w1 * (float)e1[3];
  *(float4*)(out + i) = o;
}

extern "C" void kernel_launch(void* const* d_in, const int* in_sizes, int n_in, void* d_out,
                              int out_size, void* d_ws, size_t ws_size, hipStream_t stream) {
  const float* hidden = (const float*)d_in[0];
  const float* Wq = (const float*)d_in[2];
  const float* Wk = (const float*)d_in[3];
  const float* Wv = (const float*)d_in[4];
  const float* Wkc = (const float*)d_in[5];
  const float* Wvc = (const float*)d_in[6];
  const float* Wqa = (const float*)d_in[7];
  const float* Wqg = (const float*)d_in[8];
  const float* Wov = (const float*)d_in[9];
  const float* Wo = (const float*)d_in[10];
  const float* ln1w = (const float*)d_in[11];
  const float* ln1b = (const float*)d_in[12];
  const float* ln2w = (const float*)d_in[13];
  const float* ln2b = (const float*)d_in[14];
  const float* Wg = (const float*)d_in[15];
  const float* We1 = (const float*)d_in[16];
  const float* We2 = (const float*)d_in[17];
  const float* We3 = (const float*)d_in[18];
  const float* Ws1 = (const float*)d_in[19];
  const float* Ws2 = (const float*)d_in[20];
  const float* Ws3 = (const float*)d_in[21];
  float* out = (float*)d_out;
  (void)in_sizes; (void)n_in; (void)out_size;

  const size_t MB = 1ull << 20;
  char* base = (char*)d_ws;
  // Persistent region
  float* hbuf = (float*)(base);                 // 32MB fp32 [T,D]
  bf16* shr = (bf16*)(base + 32 * MB);          // 16MB
  int* count = (int*)(base + 48 * MB);          // 4KB
  int* permg = (int*)(base + 48 * MB + 4096);
  int* permt = (int*)(base + 48 * MB + 4096 + 131072);
  float* wslot = (float*)(base + 48 * MB + 4096 + 262144);
  float* wtqa32 = (float*)(base + 49 * MB);     // 3x 32KB contiguous (qa, kc, vc)
  float* wtov32 = (float*)(base + 49 * MB + 98304);
  float* wtqg32 = (float*)(base + 49 * MB + 131072);
  // Aliased 32MB arenas
  char* A0p = base + 50 * MB;
  char* A1p = base + 82 * MB;
  char* A2p = base + 114 * MB;
  char* A3p = base + 146 * MB;
  char* A4p = base + 178 * MB;
  char* A5p = base + 210 * MB;
  if (ws_size < 242 * MB) return;  // tripwire: failure signature absmax ~= ref absmax

  // Phase A: LN + QKV projections (plane GEMMs)
  bf16* xln_h = (bf16*)A0p;                  // 16MB [T][D]
  bf16* xln_l = (bf16*)(A0p + 16 * MB);      // 16MB
  bf16* wtqkv = (bf16*)A1p;                  // 48MB: 3x (hi 8MB + lo 8MB), A1..A2
  float* qb = (float*)A3p;                   // 3x 32MB fp32 contiguous (qb,kb,vb)
  float* kb = (float*)A4p;
  // Phase B: per-head projections + attention
  bf16* qab_h = (bf16*)A1p;                  // z-strided planes: qab (A1), kcb (A1+16MB)
  bf16* qab_l = (bf16*)(A1p + 8 * MB);
  bf16* kcb_h = (bf16*)(A1p + 16 * MB);
  bf16* kcb_l = (bf16*)(A1p + 24 * MB);
  float* vcb = (float*)A2p;                  // 16MB fp32 [TH][64]
  bf16* vct_h = (bf16*)(A2p + 16 * MB);      // 8MB [BH][64][S]
  bf16* vct_l = (bf16*)(A2p + 24 * MB);
  float* qgate = (float*)A0p;                // 32MB fp32 [TH][128]
  float* attc = (float*)A3p;                 // 16MB fp32 [TH][64]
  bf16* wto_h = (bf16*)(A3p + 16 * MB);      // 8MB
  bf16* wto_l = (bf16*)(A3p + 24 * MB);
  bf16* gated_h = (bf16*)A5p;                // 16MB [T][D]
  bf16* gated_l = (bf16*)(A5p + 16 * MB);
  // Phase C: MoE
  bf16* xf = (bf16*)A1p;                     // 16MB [T][D] (dead after mid gemms)
  bf16* s1 = (bf16*)(A1p + 16 * MB);         // 16MB [T][FF] (alive until down launch)
  bf16* wts1 = (bf16*)A2p;                   // transposed shared up weights A2[0/8MB)
  bf16* wts3 = (bf16*)(A2p + 8 * MB);
  bf16* s3 = (bf16*)A3p;                     // 16MB (attc dead; consumed by silu)
  bf16* wteB_mid = (bf16*)A2p;               // 64MB: A2+A3 (wts*, s3 dead by then)
  bf16* wteB_dn = (bf16*)A2p;                // 64MB: A2+A3 (mid weights dead)
  bf16* wts2t = (bf16*)A1p;                  // 8MB at A1[0:8MB) (xf dead after mid gemms)
  bf16* mid1 = (bf16*)A4p;                   // 32MB [2T][FF]
  bf16* mid3 = (bf16*)A5p;                   // 32MB
  bf16* midg = (bf16*)A0p;                   // 32MB
  bf16* eout = (bf16*)A4p;                   // 32MB (mid1 dead after midg)

  hipMemsetAsync(count, 0, 256, stream);

  dim3 tb(32, 8);
  // Batched weight transposes.
  k_transpose_split3<<<dim3(64, 64, 3), tb, 0, stream>>>(Wq, Wk, Wv, wtqkv);
  k_transpose32b3<<<dim3(2, 4, 3), tb, 0, stream>>>(Wqa, Wkc, Wvc, wtqa32);
  k_transpose32<<<dim3(4, 4, 1), tb, 0, stream>>>(Wqg, wtqg32, 128, 128);
  k_transpose32<<<dim3(4, 2, 1), tb, 0, stream>>>(Wov, wtov32, 64, 128);

  k_ln32_split<<<T_, 256, 0, stream>>>(hidden, ln1w, ln1b, xln_h, xln_l);

  // QKV projections fused (z=3), bit-identical to three k_gemm32s<0> launches.
  k_gemm32s_qkv<<<dim3(16, 32, 3), 256, 0, stream>>>(xln_h, xln_l, wtqkv, qb);

  k_rope32<<<8192, 256, 0, stream>>>(qb, kb);

  // Per-head projections fused (z=3): qab/kcb plane outputs, vcb fp32.
  k_projn64<<<dim3(1, 512, 3), 256, 0, stream>>>(qb, wtqa32, qab_h, vcb);
  k_gemm32<0><<<dim3(1, 512, 1), 256, 0, stream>>>(qb, 128, wtqg32, 128, qgate, 128, TH_, 128, 128, nullptr, nullptr);

  k_tr_v32s<<<dim3(64, 2, 32), tb, 0, stream>>>(vcb, vct_h, vct_l);
  k_transpose_split<<<dim3(64, 64, 1), tb, 0, stream>>>(Wo, wto_h, wto_l, 2048, 2048);  // qb dead now

  k_attn32p<<<dim3(16, 32, 1), 256, 0, stream>>>(qab_h, qab_l, kcb_h, kcb_l, vct_h, vct_l, attc);

  // bf16 shared-expert up weights (A2 free after attention consumed vct).
  // (third slot reused by mid transposes later; Ws2 is transposed in the down phase)
  k_transpose_sh3<<<dim3(64, 64, 3), tb, 0, stream>>>(Ws1, Ws3, Ws2, wts1);

  // Uplift GEMM with fused silu-gate epilogue: gated = silu(qgate) * (attc@Wov^T),
  // split-stored directly (bit-identical to the old uplift+silu32_split pair).
  k_gemm32<3><<<dim3(1, 512, 1), 256, 0, stream>>>(attc, 64, wtov32, 64, qgate, 128, TH_, 128, 64, gated_h, gated_l);
  k_gemm32s<1><<<dim3(16, 32, 1), 256, 0, stream>>>(gated_h, gated_l, 2048, wto_h, wto_l, 2048, hbuf, 2048, T_, 2048, 2048, hidden);

  k_router<<<T_, 256, 0, stream>>>(hbuf, ln2w, ln2b, Wg, xf, count, permg, permt, wslot);

  // Shared-expert up projections fused (z=2), then silu in place (smid -> s1).
  k_gemm_sh<<<dim3(16, 32, 2), 256, 0, stream>>>(xf, wts1, wts3, s1, s3);
  k_silu_mul<<<4096, 256, 0, stream>>>(s1, s3, s1, (long)T_ * 2048);

  // Routed experts, mid: 4 experts x {We1, We3} per launch (z=8; wteB spans A2+A3).
  for (int p = 0; p < 2; p++) {
    k_transpose_moe<<<dim3(64, 64, 8), tb, 0, stream>>>(We1, We3, wteB_mid, 4 * p);
    k_gemm_moe<<<dim3(16, 32, 8), 256, 0, stream>>>(xf, 2048, wteB_mid, mid1, mid3, 2048, 2048, 2048, permt, permg, count, 4 * p);
  }
  k_silu_mul<<<8192, 256, 0, stream>>>(mid1, mid3, midg, (long)2 * T_ * 2048);

  // Down-projection mega launch: 8 experts + shared shr in one z=9 launch.
  k_transpose_moe2<<<dim3(64, 64, 9), tb, 0, stream>>>(We2, Ws2, wteB_dn, wts2t);
  k_gemm_moe_dn<<<dim3(16, 32, 9), 256, 0, stream>>>(midg, s1, wteB_dn, wts2t, eout, shr, permg, count);

  k_combine<<<8192, 256, 0, stream>>>(hbuf, shr, eout, wslot, out);
}

// Round 18
// 1509.864 us; speedup vs baseline: 1.0415x; 1.0415x over previous
//
#include <hip/hip_runtime.h>
#include <math.h>

typedef __bf16 bf16;
typedef __bf16 bf16x8 __attribute__((ext_vector_type(8)));
typedef float f32x4 __attribute__((ext_vector_type(4)));

#define B_ 2
#define S_ 2048
#define D_ 2048
#define H_ 16
#define FF_ 2048
#define E_ 8
#define T_ 4096
#define TH_ 65536
#define CAP_ 4096

#define MFMA_(a, b, c) __builtin_amdgcn_mfma_f32_16x16x32_bf16(a, b, c, 0, 0, 0)

// XOR swizzle, bf16 tiles (rows of 64 bf16 = 128B), 16B granules.
__device__ __forceinline__ int swz(int row, int byteoff) {
  return row * 128 + (byteoff ^ ((row & 7) << 4));
}
// XOR swizzle, fp32 tiles (rows of 64 f32 = 256B), 32B granules.
__device__ __forceinline__ int swzf(int row, int byteoff) {
  return row * 256 + (byteoff ^ ((row & 7) << 5));
}

// Async global->LDS 16B staging (no VGPR round-trip). HW semantics: LDS dest =
// wave-uniform base + lane*16; global source address is per-lane. We keep LDS
// linear per wave and pre-apply the XOR swizzle to the SOURCE granule (the
// swizzle is an involution), so LDS bytes are identical to the old ds_write
// path -> bit-identical fragments.
__device__ __forceinline__ void gload16(const void* g, void* l) {
  __builtin_amdgcn_global_load_lds((const __attribute__((address_space(1))) void*)g,
                                   (__attribute__((address_space(3))) void*)l, 16, 0, 0);
}

// 2-way bf16 split: x ~= h + m, 16-17 mantissa bits covered; residual ~2^-18|x|.
__device__ __forceinline__ void split2(float x, bf16& h, bf16& m) {
  h = (bf16)x;
  m = (bf16)(x - (float)h);
}

// Read 8 consecutive f32 from (swizzled) LDS, split into 2 bf16x8 planes.
__device__ __forceinline__ void frag_split(const char* p, int off, bf16x8& r0, bf16x8& r1) {
  f32x4 u = *(const f32x4*)(p + off);
  f32x4 v = *(const f32x4*)(p + off + 16);
#pragma unroll
  for (int j = 0; j < 4; j++) { bf16 a, b; split2(u[j], a, b); r0[j] = a; r1[j] = b; }
#pragma unroll
  for (int j = 0; j < 4; j++) { bf16 a, b; split2(v[j], a, b); r0[4 + j] = a; r1[4 + j] = b; }
}

// 3-product fp32-emulated dot: keeps {00,01,10}; error ~2^-18 relative.
__device__ __forceinline__ f32x4 dot3(bf16x8 a0, bf16x8 a1,
                                      bf16x8 b0, bf16x8 b1, f32x4 c) {
  c = MFMA_(a0, b0, c);
  c = MFMA_(a0, b1, c);
  c = MFMA_(a1, b0, c);
  return c;
}

__device__ __forceinline__ float blk_sum(float v, float* sbuf, int tid) {
#pragma unroll
  for (int mk = 32; mk; mk >>= 1) v += __shfl_xor(v, mk);
  __syncthreads();
  if ((tid & 63) == 0) sbuf[tid >> 6] = v;
  __syncthreads();
  return sbuf[0] + sbuf[1] + sbuf[2] + sbuf[3];
}

// fp32 [R][C] -> fp32 [C][R]
__global__ __launch_bounds__(256) void k_transpose32(const float* __restrict__ src,
                                                     float* __restrict__ dst, int R, int C) {
  __shared__ float tile[32][33];
  int tx = threadIdx.x, ty = threadIdx.y;
  int c0 = blockIdx.x * 32, r0 = blockIdx.y * 32;
#pragma unroll
  for (int j = 0; j < 32; j += 8) tile[ty + j][tx] = src[(size_t)(r0 + ty + j) * C + (c0 + tx)];
  __syncthreads();
#pragma unroll
  for (int j = 0; j < 32; j += 8)
    dst[(size_t)(c0 + ty + j) * R + (r0 + tx)] = tile[tx][ty + j];
}

// Batched fp32 [128][64] -> fp32 [64][128] x3 (z selects src; dst stride 8192 floats).
__global__ __launch_bounds__(256) void k_transpose32b3(const float* __restrict__ s0,
                                                       const float* __restrict__ s1x,
                                                       const float* __restrict__ s2,
                                                       float* __restrict__ dbase) {
  __shared__ float tile[32][33];
  int z = blockIdx.z;
  const float* src = z == 0 ? s0 : (z == 1 ? s1x : s2);
  float* dst = dbase + (size_t)z * 8192;
  int tx = threadIdx.x, ty = threadIdx.y;
  int c0 = blockIdx.x * 32, r0 = blockIdx.y * 32;
#pragma unroll
  for (int j = 0; j < 32; j += 8) tile[ty + j][tx] = src[(size_t)(r0 + ty + j) * 64 + (c0 + tx)];
  __syncthreads();
#pragma unroll
  for (int j = 0; j < 32; j += 8)
    dst[(size_t)(c0 + ty + j) * 128 + (r0 + tx)] = tile[tx][ty + j];
}

// Batched fp32 [2048][2048] -> bf16 [2048][2048]^T x3 (z selects src; dst stride 4194304).
__global__ __launch_bounds__(256) void k_transpose_sh3(const float* __restrict__ s0,
                                                       const float* __restrict__ s1x,
                                                       const float* __restrict__ s2,
                                                       bf16* __restrict__ dbase) {
  __shared__ float tile[32][33];
  int z = blockIdx.z;
  const float* src = z == 0 ? s0 : (z == 1 ? s1x : s2);
  bf16* dst = dbase + (size_t)z * 4194304;
  int tx = threadIdx.x, ty = threadIdx.y;
  int c0 = blockIdx.x * 32, r0 = blockIdx.y * 32;
#pragma unroll
  for (int j = 0; j < 32; j += 8) tile[ty + j][tx] = src[(size_t)(r0 + ty + j) * 2048 + (c0 + tx)];
  __syncthreads();
#pragma unroll
  for (int j = 0; j < 32; j += 8)
    dst[(size_t)(c0 + ty + j) * 2048 + (r0 + tx)] = (bf16)tile[tx][ty + j];
}

// Batched expert-weight transpose, fp32 [2048][2048] -> bf16 [2048][2048]^T.
// MODE 0: z=(pair,mat) -> src = (mat? W3 : W1)[eBase + pair]; MODE 1: z=expert -> W1[eBase+z].
template <int MODE>
__global__ __launch_bounds__(256) void k_transpose_moe(const float* __restrict__ W1,
                                                       const float* __restrict__ W3,
                                                       bf16* __restrict__ dstB, int eBase) {
  __shared__ float tile[32][33];
  int tx = threadIdx.x, ty = threadIdx.y;
  int z = blockIdx.z;
  const float* src;
  if (MODE == 0) src = ((z & 1) ? W3 : W1) + (size_t)(eBase + (z >> 1)) * 4194304;
  else src = W1 + (size_t)(eBase + z) * 4194304;
  bf16* dst = dstB + (size_t)z * 4194304;
  int c0 = blockIdx.x * 32, r0 = blockIdx.y * 32;
#pragma unroll
  for (int j = 0; j < 32; j += 8) tile[ty + j][tx] = src[(size_t)(r0 + ty + j) * 2048 + (c0 + tx)];
  __syncthreads();
#pragma unroll
  for (int j = 0; j < 32; j += 8)
    dst[(size_t)(c0 + ty + j) * 2048 + (r0 + tx)] = (bf16)tile[tx][ty + j];
}

// fp32 [R][C] -> two bf16 planes [C][R] (hi/lo split).
__global__ __launch_bounds__(256) void k_transpose_split(const float* __restrict__ src,
                                                         bf16* __restrict__ dh, bf16* __restrict__ dl,
                                                         int R, int C) {
  __shared__ float tile[32][33];
  int tx = threadIdx.x, ty = threadIdx.y;
  int c0 = blockIdx.x * 32, r0 = blockIdx.y * 32;
#pragma unroll
  for (int j = 0; j < 32; j += 8) tile[ty + j][tx] = src[(size_t)(r0 + ty + j) * C + (c0 + tx)];
  __syncthreads();
#pragma unroll
  for (int j = 0; j < 32; j += 8) {
    float v = tile[tx][ty + j];
    bf16 h, l;
    split2(v, h, l);
    size_t o = (size_t)(c0 + ty + j) * R + (r0 + tx);
    dh[o] = h;
    dl[o] = l;
  }
}

// Batched split-transpose for Wq/Wk/Wv (z selects src; dst stride 8388608 bf16 per plane pair).
__global__ __launch_bounds__(256) void k_transpose_split3(const float* __restrict__ s0,
                                                          const float* __restrict__ s1x,
                                                          const float* __restrict__ s2,
                                                          bf16* __restrict__ dbase) {
  __shared__ float tile[32][33];
  int z = blockIdx.z;
  const float* src = z == 0 ? s0 : (z == 1 ? s1x : s2);
  bf16* dh = dbase + (size_t)z * 8388608;
  bf16* dl = dh + 4194304;
  int tx = threadIdx.x, ty = threadIdx.y;
  int c0 = blockIdx.x * 32, r0 = blockIdx.y * 32;
#pragma unroll
  for (int j = 0; j < 32; j += 8) tile[ty + j][tx] = src[(size_t)(r0 + ty + j) * 2048 + (c0 + tx)];
  __syncthreads();
#pragma unroll
  for (int j = 0; j < 32; j += 8) {
    float v = tile[tx][ty + j];
    bf16 h, l;
    split2(v, h, l);
    size_t o = (size_t)(c0 + ty + j) * 2048 + (r0 + tx);
    dh[o] = h;
    dl[o] = l;
  }
}

// v_c fp32 [(b,s,h), r] -> vct bf16 planes [(b,h), r, s]
__global__ __launch_bounds__(256) void k_tr_v32s(const float* __restrict__ vc,
                                                 bf16* __restrict__ vh, bf16* __restrict__ vl) {
  __shared__ float tile[32][33];
  int tx = threadIdx.x, ty = threadIdx.y;
  int z = blockIdx.z;
  int s0 = blockIdx.x * 32, r0 = blockIdx.y * 32;
  int b = z >> 4, h = z & 15;
#pragma unroll
  for (int j = 0; j < 32; j += 8) {
    int s = s0 + ty + j;
    tile[ty + j][tx] = vc[((size_t)((b * S_ + s) * H_ + h)) * 64 + r0 + tx];
  }
  __syncthreads();
#pragma unroll
  for (int j = 0; j < 32; j += 8) {
    int r = r0 + ty + j;
    float v = tile[tx][ty + j];
    bf16 hh, ll;
    split2(v, hh, ll);
    size_t o = ((size_t)(z * 64 + r)) * S_ + s0 + tx;
    vh[o] = hh;
    vl[o] = ll;
  }
}

// LN -> split bf16 planes.
__global__ __launch_bounds__(256) void k_ln32_split(const float* __restrict__ x, const float* __restrict__ w,
                                                    const float* __restrict__ bb,
                                                    bf16* __restrict__ oh, bf16* __restrict__ ol) {
  __shared__ float sbuf[4];
  int row = blockIdx.x, tid = threadIdx.x;
  const float* xr = x + (size_t)row * D_;
  float v[8];
  float s = 0.f;
#pragma unroll
  for (int j = 0; j < 8; j++) { v[j] = xr[tid + 256 * j]; s += v[j]; }
  float mu = blk_sum(s, sbuf, tid) * (1.f / D_);
  float qs = 0.f;
#pragma unroll
  for (int j = 0; j < 8; j++) { float d = v[j] - mu; qs += d * d; }
  float rs = rsqrtf(blk_sum(qs, sbuf, tid) * (1.f / D_) + 1e-5f);
#pragma unroll
  for (int j = 0; j < 8; j++) {
    int c = tid + 256 * j;
    float xn = (v[j] - mu) * rs * w[c] + bb[c];
    bf16 h, l;
    split2(xn, h, l);
    oh[(size_t)row * D_ + c] = h;
    ol[(size_t)row * D_ + c] = l;
  }
}

// Plane GEMM (fp32-accurate via pre-split bf16 hi/lo planes, dot3).
// C[M,N] = (Ah+Al)[M,K] @ (Bh+Bl)[N,K]^T. EPI 0: fp32 store; 1: resid+store.
// Staging via global_load_lds (linear LDS dest, pre-swizzled source granule);
// LDS bytes identical to the old ds_write path -> bit-identical fragments.
template <int EPI>
__global__ __launch_bounds__(256) void k_gemm32s(const bf16* __restrict__ Ah, const bf16* __restrict__ Al, int lda,
                                                 const bf16* __restrict__ Bh, const bf16* __restrict__ Bl, int ldb,
                                                 float* __restrict__ C, int ldc,
                                                 int M, int N, int Kd,
                                                 const float* __restrict__ resid) {
  __shared__ __align__(16) char Ahs[16384];
  __shared__ __align__(16) char Als[16384];
  __shared__ __align__(16) char Bhs[16384];
  __shared__ __align__(16) char Bls[16384];
  int bm = blockIdx.y * 128, bn = blockIdx.x * 128;
  int tid = threadIdx.x;
  int srow = tid >> 3;
  int gsel = (((tid & 7) ^ ((tid >> 3) & 7))) * 8;  // pre-swizzled source granule (elements)
  int arow[4], brow[4];
#pragma unroll
  for (int i = 0; i < 4; i++) {
    int r = bm + srow + 32 * i;
    arow[i] = r < M ? r : (M - 1);
    int q = bn + srow + 32 * i;
    brow[i] = q < N ? q : (N - 1);
  }
  f32x4 acc[4][4] = {};
  int lane = tid & 63, w = tid >> 6, g = lane >> 4, lr = lane & 15;
  int wm = (w >> 1) * 64, wn = (w & 1) * 64;
  for (int kt = 0; kt < Kd; kt += 64) {
#pragma unroll
    for (int i = 0; i < 4; i++) {
      int lo = i * 4096 + w * 1024;  // wave-uniform linear dest
      gload16(Ah + (size_t)arow[i] * lda + kt + gsel, Ahs + lo);
      gload16(Al + (size_t)arow[i] * lda + kt + gsel, Als + lo);
      gload16(Bh + (size_t)brow[i] * ldb + kt + gsel, Bhs + lo);
      gload16(Bl + (size_t)brow[i] * ldb + kt + gsel, Bls + lo);
    }
    __syncthreads();
#pragma unroll
    for (int ks = 0; ks < 2; ks++) {
      bf16x8 ah[4], al[4], bh[4], bl[4];
#pragma unroll
      for (int m = 0; m < 4; m++) {
        ah[m] = *(const bf16x8*)(Ahs + swz(wm + m * 16 + lr, ks * 64 + g * 16));
        al[m] = *(const bf16x8*)(Als + swz(wm + m * 16 + lr, ks * 64 + g * 16));
      }
#pragma unroll
      for (int n = 0; n < 4; n++) {
        bh[n] = *(const bf16x8*)(Bhs + swz(wn + n * 16 + lr, ks * 64 + g * 16));
        bl[n] = *(const bf16x8*)(Bls + swz(wn + n * 16 + lr, ks * 64 + g * 16));
      }
#pragma unroll
      for (int m = 0; m < 4; m++)
#pragma unroll
        for (int n = 0; n < 4; n++)
          acc[m][n] = dot3(ah[m], al[m], bh[n], bl[n], acc[m][n]);
    }
    __syncthreads();
  }
#pragma unroll
  for (int m = 0; m < 4; m++)
#pragma unroll
    for (int n = 0; n < 4; n++)
#pragma unroll
      for (int r = 0; r < 4; r++) {
        int row = bm + wm + m * 16 + g * 4 + r;
        int col = bn + wn + n * 16 + lr;
        if (row < M && col < N) {
          float val = acc[m][n][r];
          if (EPI == 1) val += resid[(size_t)row * ldc + col];
          C[(size_t)row * ldc + col] = val;
        }
      }
}

// Fused QKV plane GEMM: z selects B-plane pair (stride 8388608 bf16) and C (stride 8388608 f32).
// M=4096, N=2048, K=2048 fixed; same per-output MFMA order as k_gemm32s<0>.
// global_load_lds staging (bit-identical LDS bytes).
__global__ __launch_bounds__(256) void k_gemm32s_qkv(const bf16* __restrict__ Ah, const bf16* __restrict__ Al,
                                                     const bf16* __restrict__ Bhb,
                                                     float* __restrict__ Cb) {
  int z = blockIdx.z;
  const bf16* Bh = Bhb + (size_t)z * 8388608;
  const bf16* Bl = Bh + 4194304;
  float* C = Cb + (size_t)z * 8388608;
  __shared__ __align__(16) char Ahs[16384];
  __shared__ __align__(16) char Als[16384];
  __shared__ __align__(16) char Bhs[16384];
  __shared__ __align__(16) char Bls[16384];
  int bm = blockIdx.y * 128, bn = blockIdx.x * 128;
  int tid = threadIdx.x;
  int srow = tid >> 3;
  int gsel = (((tid & 7) ^ ((tid >> 3) & 7))) * 8;
  f32x4 acc[4][4] = {};
  int lane = tid & 63, w = tid >> 6, g = lane >> 4, lr = lane & 15;
  int wm = (w >> 1) * 64, wn = (w & 1) * 64;
  for (int kt = 0; kt < 2048; kt += 64) {
#pragma unroll
    for (int i = 0; i < 4; i++) {
      int row = srow + 32 * i;
      int lo = i * 4096 + w * 1024;
      gload16(Ah + (size_t)(bm + row) * 2048 + kt + gsel, Ahs + lo);
      gload16(Al + (size_t)(bm + row) * 2048 + kt + gsel, Als + lo);
      gload16(Bh + (size_t)(bn + row) * 2048 + kt + gsel, Bhs + lo);
      gload16(Bl + (size_t)(bn + row) * 2048 + kt + gsel, Bls + lo);
    }
    __syncthreads();
#pragma unroll
    for (int ks = 0; ks < 2; ks++) {
      bf16x8 ah[4], al[4], bh[4], bl[4];
#pragma unroll
      for (int m = 0; m < 4; m++) {
        ah[m] = *(const bf16x8*)(Ahs + swz(wm + m * 16 + lr, ks * 64 + g * 16));
        al[m] = *(const bf16x8*)(Als + swz(wm + m * 16 + lr, ks * 64 + g * 16));
      }
#pragma unroll
      for (int n = 0; n < 4; n++) {
        bh[n] = *(const bf16x8*)(Bhs + swz(wn + n * 16 + lr, ks * 64 + g * 16));
        bl[n] = *(const bf16x8*)(Bls + swz(wn + n * 16 + lr, ks * 64 + g * 16));
      }
#pragma unroll
      for (int m = 0; m < 4; m++)
#pragma unroll
        for (int n = 0; n < 4; n++)
          acc[m][n] = dot3(ah[m], al[m], bh[n], bl[n], acc[m][n]);
    }
    __syncthreads();
  }
#pragma unroll
  for (int m = 0; m < 4; m++)
#pragma unroll
    for (int n = 0; n < 4; n++)
#pragma unroll
      for (int r = 0; r < 4; r++) {
        int row = bm + wm + m * 16 + g * 4 + r;
        int col = bn + wn + n * 16 + lr;
        C[(size_t)row * 2048 + col] = acc[m][n][r];
      }
}

// fp32-in GEMM with in-kernel split. EPI 0: fp32 store.
// EPI 3: fused silu-gate epilogue: gated = silu(Cin[idx]) * acc, split-stored
// to Ch/Cl (Cin = qgate passed via the C pointer, read-only).
// Staging via global_load_lds with pre-swizzled fp32 source granule.
template <int EPI>
__global__ __launch_bounds__(256) void k_gemm32(const float* __restrict__ A, int lda,
                                                const float* __restrict__ Bt, int ldb,
                                                float* __restrict__ C, int ldc,
                                                int M, int N, int Kd,
                                                bf16* __restrict__ Ch, bf16* __restrict__ Cl) {
  __shared__ __align__(16) char As[32768];
  __shared__ __align__(16) char Bs[32768];
  int bm = blockIdx.y * 128, bn = blockIdx.x * 128;
  int tid = threadIdx.x;
  int g16 = tid & 15;
  int rquot = tid >> 4;  // row base per pass (0..15)
  int gsrcf = (((g16 >> 1) ^ (rquot & 7)) * 8) + ((g16 & 1) * 4);  // source float offset
  f32x4 acc[4][4] = {};
  int lane = tid & 63, w = tid >> 6, g = lane >> 4, lr = lane & 15;
  int wm = (w >> 1) * 64, wn = (w & 1) * 64;
  for (int kt = 0; kt < Kd; kt += 64) {
#pragma unroll
    for (int i = 0; i < 8; i++) {
      int rloc = rquot + 16 * i;
      int ra = bm + rloc; ra = ra < M ? ra : (M - 1);
      int rb = bn + rloc; rb = rb < N ? rb : (N - 1);
      int lo = i * 4096 + w * 1024;
      gload16(A + (size_t)ra * lda + kt + gsrcf, As + lo);
      gload16(Bt + (size_t)rb * ldb + kt + gsrcf, Bs + lo);
    }
    __syncthreads();
#pragma unroll
    for (int ks = 0; ks < 2; ks++) {
      bf16x8 a0[4], a1[4], b0[4], b1[4];
#pragma unroll
      for (int m = 0; m < 4; m++)
        frag_split(As, swzf(wm + m * 16 + lr, ks * 128 + g * 32), a0[m], a1[m]);
#pragma unroll
      for (int n = 0; n < 4; n++)
        frag_split(Bs, swzf(wn + n * 16 + lr, ks * 128 + g * 32), b0[n], b1[n]);
#pragma unroll
      for (int m = 0; m < 4; m++)
#pragma unroll
        for (int n = 0; n < 4; n++)
          acc[m][n] = dot3(a0[m], a1[m], b0[n], b1[n], acc[m][n]);
    }
    __syncthreads();
  }
#pragma unroll
  for (int m = 0; m < 4; m++)
#pragma unroll
    for (int n = 0; n < 4; n++)
#pragma unroll
      for (int r = 0; r < 4; r++) {
        int row = bm + wm + m * 16 + g * 4 + r;
        int col = bn + wn + n * 16 + lr;
        if (row < M && col < N) {
          if (EPI == 3) {
            float up = acc[m][n][r];
            float x = C[(size_t)row * ldc + col];
            float gg = x / (1.f + expf(-x)) * up;
            bf16 h, l;
            split2(gg, h, l);
            Ch[(size_t)row * ldc + col] = h;
            Cl[(size_t)row * ldc + col] = l;
          } else {
            C[(size_t)row * ldc + col] = acc[m][n][r];
          }
        }
      }
}

// Fused per-head projections, 128x64 tile (48KB LDS): z=0 q_a (plane out),
// z=1 k_c (plane out), z=2 v_c (fp32 out). A stride 8388608 f32; B stride 8192 f32;
// plane-out stride 8388608 bf16. global_load_lds staging (bit-identical bytes).
__global__ __launch_bounds__(256) void k_projn64(const float* __restrict__ Ab,
                                                 const float* __restrict__ Btb,
                                                 bf16* __restrict__ Pb,
                                                 float* __restrict__ Vb) {
  int z = blockIdx.z;
  const float* A = Ab + (size_t)z * 8388608;
  const float* Bt = Btb + (size_t)z * 8192;
  __shared__ __align__(16) char As[32768];
  __shared__ __align__(16) char Bs[16384];
  int bm = blockIdx.y * 128;
  int tid = threadIdx.x;
  int lane = tid & 63, w = tid >> 6, g = lane >> 4, lr = lane & 15;
  int g16 = tid & 15;
  int rquot = tid >> 4;
  int gsrcf = (((g16 >> 1) ^ (rquot & 7)) * 8) + ((g16 & 1) * 4);
  f32x4 acc[2][4] = {};
  for (int kt = 0; kt < 128; kt += 64) {
#pragma unroll
    for (int i = 0; i < 8; i++) {
      int rloc = rquot + 16 * i;
      int lo = i * 4096 + w * 1024;
      gload16(A + (size_t)(bm + rloc) * 128 + kt + gsrcf, As + lo);
    }
#pragma unroll
    for (int i = 0; i < 4; i++) {
      int rloc = rquot + 16 * i;
      int lo = i * 4096 + w * 1024;
      gload16(Bt + (size_t)rloc * 128 + kt + gsrcf, Bs + lo);
    }
    __syncthreads();
#pragma unroll
    for (int ks = 0; ks < 2; ks++) {
      bf16x8 a0[2], a1[2], b0[4], b1[4];
#pragma unroll
      for (int m = 0; m < 2; m++)
        frag_split(As, swzf(w * 32 + m * 16 + lr, ks * 128 + g * 32), a0[m], a1[m]);
#pragma unroll
      for (int n = 0; n < 4; n++)
        frag_split(Bs, swzf(n * 16 + lr, ks * 128 + g * 32), b0[n], b1[n]);
#pragma unroll
      for (int m = 0; m < 2; m++)
#pragma unroll
        for (int n = 0; n < 4; n++)
          acc[m][n] = dot3(a0[m], a1[m], b0[n], b1[n], acc[m][n]);
    }
    __syncthreads();
  }
  bf16* Ph = Pb + (size_t)z * 8388608;
  bf16* Pl = Ph + 4194304;
#pragma unroll
  for (int m = 0; m < 2; m++)
#pragma unroll
    for (int n = 0; n < 4; n++)
#pragma unroll
      for (int r = 0; r < 4; r++) {
        int row = bm + w * 32 + m * 16 + g * 4 + r;
        int col = n * 16 + lr;
        size_t o = (size_t)row * 64 + col;
        float val = acc[m][n][r];
        if (z == 2) {
          Vb[o] = val;
        } else {
          bf16 h, l;
          split2(val, h, l);
          Ph[o] = h;
          Pl[o] = l;
        }
      }
}

__global__ __launch_bounds__(256) void k_rope32(float* __restrict__ q, float* __restrict__ k) {
  int idx = blockIdx.x * 256 + threadIdx.x;  // TH_*32 threads
  int i = idx & 31, rowth = idx >> 5;
  int s = (rowth >> 4) & (S_ - 1);
  size_t base = (size_t)rowth * 128;
  float freq = expf(-0.28782313662425576f * (float)i);  // ln(10000)/32
  float ang = (float)s * freq;
  float sn, cs;
  sincosf(ang, &sn, &cs);
  float q1 = q[base + i], q2 = q[base + i + 32];
  q[base + i] = q1 * cs - q2 * sn;
  q[base + i + 32] = q2 * cs + q1 * sn;
  float k1 = k[base + i], k2 = k[base + i + 32];
  k[base + i] = k1 * cs - k2 * sn;
  k[base + i + 32] = k2 * cs + k1 * sn;
}

// Flash attention, fp32-accurate via pre-split bf16 hi/lo planes for Q,K,V.
// R13-exact (best-known config): two-plane P, dot3 PV, 64KB LDS, expf,
// ds_write-staged K/V (attn is barrier-bound; gload_lds staging was neutral).
// XCD-aware (qt,bh) remap (mapping-only).
// NOTE: attention values feed the MoE router's top-2 selection; any numeric
// perturbation here flips borderline tokens' expert choice (absmax ~1.2).
// Do not change the math in this kernel.
__global__ __launch_bounds__(256) void k_attn32p(const bf16* __restrict__ qh, const bf16* __restrict__ ql,
                                                 const bf16* __restrict__ kh, const bf16* __restrict__ kl,
                                                 const bf16* __restrict__ vh, const bf16* __restrict__ vl,
                                                 float* __restrict__ attc) {
  __shared__ __align__(16) char L[65536];
  int lin = blockIdx.x + 16 * blockIdx.y;
  int xcd = lin & 7, j = lin >> 3;
  int bh = xcd * 4 + (j & 3);
  int qt = j >> 2;
  int b = bh >> 4, h = bh & 15;
  int tid = threadIdx.x, lane = tid & 63, w = tid >> 6, g = lane >> 4, lr = lane & 15;
  int s0 = qt * 128;
  int srow = tid >> 3, scol = (tid & 7) * 8;
  char* Qsh = L;
  char* Qsl = L + 16384;
#pragma unroll
  for (int i = 0; i < 4; i++) {
    int row = srow + 32 * i;
    size_t goff = ((size_t)((b * S_ + s0 + row) * H_ + h)) * 64 + scol;
    int o = swz(row, scol * 2);
    *(uint4*)(Qsh + o) = *(const uint4*)(qh + goff);
    *(uint4*)(Qsl + o) = *(const uint4*)(ql + goff);
  }
  __syncthreads();
  bf16x8 qf0[2][2], qf1[2][2];
#pragma unroll
  for (int m = 0; m < 2; m++)
#pragma unroll
    for (int ks = 0; ks < 2; ks++) {
      qf0[m][ks] = *(const bf16x8*)(Qsh + swz(w * 32 + m * 16 + lr, ks * 64 + g * 16));
      qf1[m][ks] = *(const bf16x8*)(Qsl + swz(w * 32 + m * 16 + lr, ks * 64 + g * 16));
    }
  __syncthreads();  // all waves done reading Q before K/V overwrite
  char* Ksh = L;
  char* Ksl = L + 8192;
  char* Vsh = L + 16384;
  char* Vsl = L + 24576;
  char* Ph = L + 32768 + w * 8192;
  char* Pl = Ph + 4096;
  f32x4 acc[2][4] = {};
  float mrun[2][4], lrun[2][4];
#pragma unroll
  for (int m = 0; m < 2; m++)
#pragma unroll
    for (int r = 0; r < 4; r++) { mrun[m][r] = -1e30f; lrun[m][r] = 0.f; }
  for (int kt = 0; kt < S_; kt += 64) {
#pragma unroll
    for (int i = 0; i < 2; i++) {
      int rr = srow + 32 * i;
      size_t koff = ((size_t)((b * S_ + kt + rr) * H_ + h)) * 64 + scol;
      size_t voff = ((size_t)(bh * 64 + rr)) * S_ + kt + scol;
      int o = swz(rr, scol * 2);
      *(uint4*)(Ksh + o) = *(const uint4*)(kh + koff);
      *(uint4*)(Ksl + o) = *(const uint4*)(kl + koff);
      *(uint4*)(Vsh + o) = *(const uint4*)(vh + voff);
      *(uint4*)(Vsl + o) = *(const uint4*)(vl + voff);
    }
    __syncthreads();
    f32x4 sc[2][4] = {};
#pragma unroll
    for (int ks = 0; ks < 2; ks++) {
      bf16x8 k0[4], k1[4];
#pragma unroll
      for (int n = 0; n < 4; n++) {
        k0[n] = *(const bf16x8*)(Ksh + swz(n * 16 + lr, ks * 64 + g * 16));
        k1[n] = *(const bf16x8*)(Ksl + swz(n * 16 + lr, ks * 64 + g * 16));
      }
      __builtin_amdgcn_s_setprio(1);
#pragma unroll
      for (int m = 0; m < 2; m++)
#pragma unroll
        for (int n = 0; n < 4; n++)
          sc[m][n] = dot3(qf0[m][ks], qf1[m][ks], k0[n], k1[n], sc[m][n]);
      __builtin_amdgcn_s_setprio(0);
    }
#pragma unroll
    for (int m = 0; m < 2; m++)
#pragma unroll
      for (int r = 0; r < 4; r++) {
        float a0 = sc[m][0][r] * 0.125f, a1 = sc[m][1][r] * 0.125f;
        float a2 = sc[m][2][r] * 0.125f, a3 = sc[m][3][r] * 0.125f;
        float mx = fmaxf(fmaxf(a0, a1), fmaxf(a2, a3));
#pragma unroll
        for (int mk = 1; mk < 16; mk <<= 1) mx = fmaxf(mx, __shfl_xor(mx, mk));
        float mo = mrun[m][r];
        float mn = fmaxf(mo, mx);
        float f = expf(mo - mn);
        float p0 = expf(a0 - mn), p1 = expf(a1 - mn), p2 = expf(a2 - mn), p3 = expf(a3 - mn);
        int prow = m * 16 + g * 4 + r;
        bf16 h0, l0, h1, l1, h2, l2, h3, l3;
        split2(p0, h0, l0);
        split2(p1, h1, l1);
        split2(p2, h2, l2);
        split2(p3, h3, l3);
        *(bf16*)(Ph + swz(prow, lr * 2)) = h0;
        *(bf16*)(Pl + swz(prow, lr * 2)) = l0;
        *(bf16*)(Ph + swz(prow, 32 + lr * 2)) = h1;
        *(bf16*)(Pl + swz(prow, 32 + lr * 2)) = l1;
        *(bf16*)(Ph + swz(prow, 64 + lr * 2)) = h2;
        *(bf16*)(Pl + swz(prow, 64 + lr * 2)) = l2;
        *(bf16*)(Ph + swz(prow, 96 + lr * 2)) = h3;
        *(bf16*)(Pl + swz(prow, 96 + lr * 2)) = l3;
        float ps = p0 + p1 + p2 + p3;
#pragma unroll
        for (int mk = 1; mk < 16; mk <<= 1) ps += __shfl_xor(ps, mk);
        lrun[m][r] = lrun[m][r] * f + ps;
        mrun[m][r] = mn;
#pragma unroll
        for (int n = 0; n < 4; n++) acc[m][n][r] *= f;
      }
#pragma unroll
    for (int ks = 0; ks < 2; ks++) {
      bf16x8 p0f[2], p1f[2], v0f[4], v1f[4];
#pragma unroll
      for (int m = 0; m < 2; m++) {
        p0f[m] = *(const bf16x8*)(Ph + swz(m * 16 + lr, ks * 64 + g * 16));
        p1f[m] = *(const bf16x8*)(Pl + swz(m * 16 + lr, ks * 64 + g * 16));
      }
#pragma unroll
      for (int n = 0; n < 4; n++) {
        v0f[n] = *(const bf16x8*)(Vsh + swz(n * 16 + lr, ks * 64 + g * 16));
        v1f[n] = *(const bf16x8*)(Vsl + swz(n * 16 + lr, ks * 64 + g * 16));
      }
      __builtin_amdgcn_s_setprio(1);
#pragma unroll
      for (int m = 0; m < 2; m++)
#pragma unroll
        for (int n = 0; n < 4; n++)
          acc[m][n] = dot3(p0f[m], p1f[m], v0f[n], v1f[n], acc[m][n]);
      __builtin_amdgcn_s_setprio(0);
    }
    __syncthreads();
  }
#pragma unroll
  for (int m = 0; m < 2; m++)
#pragma unroll
    for (int n = 0; n < 4; n++)
#pragma unroll
      for (int r = 0; r < 4; r++) {
        int s = s0 + w * 32 + m * 16 + g * 4 + r;
        attc[((size_t)((b * S_ + s) * H_ + h)) * 64 + n * 16 + lr] = acc[m][n][r] / lrun[m][r];
      }
}

// LN2 (fp32) + router logits (fp32) + top-2 + list append; writes xf bf16.
__global__ __launch_bounds__(256) void k_router(const float* __restrict__ hbuf,
                                                const float* __restrict__ w2, const float* __restrict__ b2,
                                                const float* __restrict__ Wg, bf16* __restrict__ xf,
                                                int* __restrict__ count, int* __restrict__ permg,
                                                int* __restrict__ permt, float* __restrict__ wslot) {
  __shared__ float sbuf[4];
  int t = blockIdx.x, tid = threadIdx.x;
  const float* hr = hbuf + (size_t)t * D_;
  float v[8];
  float s = 0.f;
#pragma unroll
  for (int j = 0; j < 8; j++) { v[j] = hr[tid + 256 * j]; s += v[j]; }
  float mu = blk_sum(s, sbuf, tid) * (1.f / D_);
  float qs = 0.f;
#pragma unroll
  for (int j = 0; j < 8; j++) { float d = v[j] - mu; qs += d * d; }
  float rs = rsqrtf(blk_sum(qs, sbuf, tid) * (1.f / D_) + 1e-5f);
  float le[8] = {0, 0, 0, 0, 0, 0, 0, 0};
#pragma unroll
  for (int j = 0; j < 8; j++) {
    int c = tid + 256 * j;
    float xn = (v[j] - mu) * rs * w2[c] + b2[c];
    xf[(size_t)t * D_ + c] = (bf16)xn;
    const float* wr = Wg + (size_t)c * 8;
#pragma unroll
    for (int e = 0; e < 8; e++) le[e] += xn * wr[e];
  }
#pragma unroll
  for (int e = 0; e < 8; e++) le[e] = blk_sum(le[e], sbuf, tid);
  if (tid == 0) {
    float mx = le[0];
    for (int e = 1; e < 8; e++) mx = fmaxf(mx, le[e]);
    float p[8], sum = 0.f;
    for (int e = 0; e < 8; e++) { p[e] = expf(le[e] - mx); sum += p[e]; }
    int i0 = 0;
    for (int e = 1; e < 8; e++) if (p[e] > p[i0]) i0 = e;
    int i1 = (i0 == 0) ? 1 : 0;
    for (int e = 0; e < 8; e++) if (e != i0 && p[e] > p[i1]) i1 = e;
    float inv = 1.f / (p[i0] + p[i1]);
    int pos0 = atomicAdd(&count[i0], 1);
    permg[i0 * CAP_ + pos0] = 2 * t;
    permt[i0 * CAP_ + pos0] = t;
    int pos1 = atomicAdd(&count[i1], 1);
    permg[i1 * CAP_ + pos1] = 2 * t + 1;
    permt[i1 * CAP_ + pos1] = t;
    wslot[2 * t] = p[i0] * inv;
    wslot[2 * t + 1] = p[i1] * inv;
  }
}

// bf16 GEMM: C[M,N] = A[M,K] @ Bt[N,K]^T (optional gather). global_load_lds staging.
template <bool GATHER>
__global__ __launch_bounds__(256) void k_gemm(const bf16* __restrict__ A, int lda,
                                              const bf16* __restrict__ Bt, int ldb,
                                              bf16* __restrict__ C, int ldc, int M, int N, int Kd,
                                              const int* __restrict__ amap,
                                              const int* __restrict__ cmap,
                                              const int* __restrict__ countp) {
  int Mz = countp ? countp[0] : M;
  int bm = blockIdx.y * 128, bn = blockIdx.x * 128;
  if (bm >= Mz) return;
  __shared__ __align__(16) char As[16384];
  __shared__ __align__(16) char Bs[16384];
  int tid = threadIdx.x;
  int srow = tid >> 3;
  int gsel = (((tid & 7) ^ ((tid >> 3) & 7))) * 8;
  int arow[4], brow[4];
#pragma unroll
  for (int i = 0; i < 4; i++) {
    int r = bm + srow + 32 * i;
    if (GATHER) { int rc = r < Mz ? r : (Mz - 1); arow[i] = amap[rc]; }
    else { arow[i] = r < M ? r : (M - 1); }
    int bq = bn + srow + 32 * i;
    brow[i] = bq < N ? bq : (N - 1);
  }
  f32x4 acc[4][4] = {};
  int lane = tid & 63, w = tid >> 6, g = lane >> 4, lr = lane & 15;
  int wm = (w >> 1) * 64, wn = (w & 1) * 64;
  for (int kt = 0; kt < Kd; kt += 64) {
#pragma unroll
    for (int i = 0; i < 4; i++) {
      int lo = i * 4096 + w * 1024;
      gload16(A + (size_t)arow[i] * lda + kt + gsel, As + lo);
      gload16(Bt + (size_t)brow[i] * ldb + kt + gsel, Bs + lo);
    }
    __syncthreads();
#pragma unroll
    for (int ks = 0; ks < 2; ks++) {
      bf16x8 af[4], bfr[4];
#pragma unroll
      for (int m = 0; m < 4; m++) af[m] = *(const bf16x8*)(As + swz(wm + m * 16 + lr, ks * 64 + g * 16));
#pragma unroll
      for (int n = 0; n < 4; n++) bfr[n] = *(const bf16x8*)(Bs + swz(wn + n * 16 + lr, ks * 64 + g * 16));
#pragma unroll
      for (int m = 0; m < 4; m++)
#pragma unroll
        for (int n = 0; n < 4; n++)
          acc[m][n] = MFMA_(af[m], bfr[n], acc[m][n]);
    }
    __syncthreads();
  }
#pragma unroll
  for (int m = 0; m < 4; m++)
#pragma unroll
    for (int n = 0; n < 4; n++)
#pragma unroll
      for (int r = 0; r < 4; r++) {
        int row = bm + wm + m * 16 + g * 4 + r;
        int col = bn + wn + n * 16 + lr;
        if (row < Mz && col < N) {
          size_t orow = cmap ? (size_t)cmap[row] : (size_t)row;
          C[orow * ldc + col] = (bf16)acc[m][n][r];
        }
      }
}

// Shared-expert up projections fused, z=2: C_z = xf @ Bt_z^T (bf16, no gather).
// Same body as k_gemm<false>; z selects Bt/C. Bit-identical per-output math.
__global__ __launch_bounds__(256) void k_gemm_sh(const bf16* __restrict__ A,
                                                 const bf16* __restrict__ Bt0, const bf16* __restrict__ Bt1,
                                                 bf16* __restrict__ C0, bf16* __restrict__ C1) {
  int z = blockIdx.z;
  const bf16* Bt = z ? Bt1 : Bt0;
  bf16* C = z ? C1 : C0;
  __shared__ __align__(16) char As[16384];
  __shared__ __align__(16) char Bs[16384];
  int bm = blockIdx.y * 128, bn = blockIdx.x * 128;
  int tid = threadIdx.x;
  int srow = tid >> 3;
  int gsel = (((tid & 7) ^ ((tid >> 3) & 7))) * 8;
  f32x4 acc[4][4] = {};
  int lane = tid & 63, w = tid >> 6, g = lane >> 4, lr = lane & 15;
  int wm = (w >> 1) * 64, wn = (w & 1) * 64;
  for (int kt = 0; kt < 2048; kt += 64) {
#pragma unroll
    for (int i = 0; i < 4; i++) {
      int row = srow + 32 * i;
      int lo = i * 4096 + w * 1024;
      gload16(A + (size_t)(bm + row) * 2048 + kt + gsel, As + lo);
      gload16(Bt + (size_t)(bn + row) * 2048 + kt + gsel, Bs + lo);
    }
    __syncthreads();
#pragma unroll
    for (int ks = 0; ks < 2; ks++) {
      bf16x8 af[4], bfr[4];
#pragma unroll
      for (int m = 0; m < 4; m++) af[m] = *(const bf16x8*)(As + swz(wm + m * 16 + lr, ks * 64 + g * 16));
#pragma unroll
      for (int n = 0; n < 4; n++) bfr[n] = *(const bf16x8*)(Bs + swz(wn + n * 16 + lr, ks * 64 + g * 16));
#pragma unroll
      for (int m = 0; m < 4; m++)
#pragma unroll
        for (int n = 0; n < 4; n++)
          acc[m][n] = MFMA_(af[m], bfr[n], acc[m][n]);
    }
    __syncthreads();
  }
#pragma unroll
  for (int m = 0; m < 4; m++)
#pragma unroll
    for (int n = 0; n < 4; n++)
#pragma unroll
      for (int r = 0; r < 4; r++) {
        int row = bm + wm + m * 16 + g * 4 + r;
        int col = bn + wn + n * 16 + lr;
        C[(size_t)row * 2048 + col] = (bf16)acc[m][n][r];
      }
}

// Fused routed-expert GEMM: blockIdx.z selects expert (and matrix).
// MODE 0 (mid): z=(pair,mat); e=eBase+(z>>1); gather=permt[e], scatter=permg[e];
//               Bt = wteB[z]; C = mat? C1 : C0.
// MODE 1 (out): z=expert offset; e=eBase+z; gather=scatter=permg[e]; C=C0.
// global_load_lds staging.
template <int MODE>
__global__ __launch_bounds__(256) void k_gemm_moe(const bf16* __restrict__ A, int lda,
                                                  const bf16* __restrict__ wteB,
                                                  bf16* __restrict__ C0, bf16* __restrict__ C1, int ldc,
                                                  int N, int Kd,
                                                  const int* __restrict__ permt, const int* __restrict__ permg,
                                                  const int* __restrict__ count, int eBase) {
  int z = blockIdx.z;
  int e;
  const int* amap;
  const int* cmap;
  bf16* C;
  if (MODE == 0) {
    e = eBase + (z >> 1);
    amap = permt + e * CAP_;
    cmap = permg + e * CAP_;
    C = (z & 1) ? C1 : C0;
  } else {
    e = eBase + z;
    amap = permg + e * CAP_;
    cmap = permg + e * CAP_;
    C = C0;
  }
  const bf16* Bt = wteB + (size_t)z * 4194304;
  int Mz = count[e];
  int bm = blockIdx.y * 128, bn = blockIdx.x * 128;
  if (bm >= Mz) return;
  __shared__ __align__(16) char As[16384];
  __shared__ __align__(16) char Bs[16384];
  int tid = threadIdx.x;
  int srow = tid >> 3;
  int gsel = (((tid & 7) ^ ((tid >> 3) & 7))) * 8;
  int arow[4], brow[4];
#pragma unroll
  for (int i = 0; i < 4; i++) {
    int r = bm + srow + 32 * i;
    int rc = r < Mz ? r : (Mz - 1);
    arow[i] = amap[rc];
    int bq = bn + srow + 32 * i;
    brow[i] = bq < N ? bq : (N - 1);
  }
  f32x4 acc[4][4] = {};
  int lane = tid & 63, w = tid >> 6, g = lane >> 4, lr = lane & 15;
  int wm = (w >> 1) * 64, wn = (w & 1) * 64;
  for (int kt = 0; kt < Kd; kt += 64) {
#pragma unroll
    for (int i = 0; i < 4; i++) {
      int lo = i * 4096 + w * 1024;
      gload16(A + (size_t)arow[i] * lda + kt + gsel, As + lo);
      gload16(Bt + (size_t)brow[i] * 2048 + kt + gsel, Bs + lo);
    }
    __syncthreads();
#pragma unroll
    for (int ks = 0; ks < 2; ks++) {
      bf16x8 af[4], bfr[4];
#pragma unroll
      for (int m = 0; m < 4; m++) af[m] = *(const bf16x8*)(As + swz(wm + m * 16 + lr, ks * 64 + g * 16));
#pragma unroll
      for (int n = 0; n < 4; n++) bfr[n] = *(const bf16x8*)(Bs + swz(wn + n * 16 + lr, ks * 64 + g * 16));
#pragma unroll
      for (int m = 0; m < 4; m++)
#pragma unroll
        for (int n = 0; n < 4; n++)
          acc[m][n] = MFMA_(af[m], bfr[n], acc[m][n]);
    }
    __syncthreads();
  }
#pragma unroll
  for (int m = 0; m < 4; m++)
#pragma unroll
    for (int n = 0; n < 4; n++)
#pragma unroll
      for (int r = 0; r < 4; r++) {
        int row = bm + wm + m * 16 + g * 4 + r;
        int col = bn + wn + n * 16 + lr;
        if (row < Mz && col < N) {
          C[(size_t)cmap[row] * ldc + col] = (bf16)acc[m][n][r];
        }
      }
}

__global__ __launch_bounds__(256) void k_silu_mul(const bf16* __restrict__ a, const bf16* __restrict__ b,
                                                  bf16* __restrict__ c, long n) {
  long i = ((long)blockIdx.x * 256 + threadIdx.x) * 8;
  if (i >= n) return;
  bf16x8 av = *(const bf16x8*)(a + i);
  bf16x8 bv = *(const bf16x8*)(b + i);
  bf16x8 cv;
#pragma unroll
  for (int j = 0; j < 8; j++) {
    float x = (float)av[j];
    float y = (float)bv[j];
    cv[j] = (bf16)(x / (1.f + expf(-x)) * y);
  }
  *(bf16x8*)(c + i) = cv;
}

__global__ __launch_bounds__(256) void k_combine(const float* __restrict__ hbuf, const bf16* __restrict__ shr,
                                                 const bf16* __restrict__ eout, const float* __restrict__ wslot,
                                                 float* __restrict__ out) {
  long i = ((long)blockIdx.x * 256 + threadIdx.x) * 4;
  int t = (int)(i >> 11);
  int c = (int)(i & (D_ - 1));
  float w0 = wslot[2 * t], w1 = wslot[2 * t + 1];
  float4 hv = *(const float4*)(hbuf + i);
  const bf16* s4 = shr + i;
  const bf16* e0 = eout + ((size_t)(2 * t)) * D_ + c;
  const bf16* e1 = e0 + D_;
  float4 o;
  o.x = hv.x + (float)s4[0] + w0 * (float)e0[0] + w1 * (float)e1[0];
  o.y = hv.y + (float)s4[1] + w0 * (float)e0[1] + w1 * (float)e1[1];
  o.z = hv.z + (float)s4[2] + w0 * (float)e0[2] + w1 * (float)e1[2];
  o.w = hv.w + (float)s4[3] + w0 * (float)e0[3] + w1 * (float)e1[3];
  *(float4*)(out + i) = o;
}

extern "C" void kernel_launch(void* const* d_in, const int* in_sizes, int n_in, void* d_out,
                              int out_size, void* d_ws, size_t ws_size, hipStream_t stream) {
  const float* hidden = (const float*)d_in[0];
  const float* Wq = (const float*)d_in[2];
  const float* Wk = (const float*)d_in[3];
  const float* Wv = (const float*)d_in[4];
  const float* Wkc = (const float*)d_in[5];
  const float* Wvc = (const float*)d_in[6];
  const float* Wqa = (const float*)d_in[7];
  const float* Wqg = (const float*)d_in[8];
  const float* Wov = (const float*)d_in[9];
  const float* Wo = (const float*)d_in[10];
  const float* ln1w = (const float*)d_in[11];
  const float* ln1b = (const float*)d_in[12];
  const float* ln2w = (const float*)d_in[13];
  const float* ln2b = (const float*)d_in[14];
  const float* Wg = (const float*)d_in[15];
  const float* We1 = (const float*)d_in[16];
  const float* We2 = (const float*)d_in[17];
  const float* We3 = (const float*)d_in[18];
  const float* Ws1 = (const float*)d_in[19];
  const float* Ws2 = (const float*)d_in[20];
  const float* Ws3 = (const float*)d_in[21];
  float* out = (float*)d_out;
  (void)in_sizes; (void)n_in; (void)out_size;

  const size_t MB = 1ull << 20;
  char* base = (char*)d_ws;
  // Persistent region
  float* hbuf = (float*)(base);                 // 32MB fp32 [T,D]
  bf16* shr = (bf16*)(base + 32 * MB);          // 16MB
  int* count = (int*)(base + 48 * MB);          // 4KB
  int* permg = (int*)(base + 48 * MB + 4096);
  int* permt = (int*)(base + 48 * MB + 4096 + 131072);
  float* wslot = (float*)(base + 48 * MB + 4096 + 262144);
  float* wtqa32 = (float*)(base + 49 * MB);     // 3x 32KB contiguous (qa, kc, vc)
  float* wtov32 = (float*)(base + 49 * MB + 98304);
  float* wtqg32 = (float*)(base + 49 * MB + 131072);
  // Aliased 32MB arenas
  char* A0p = base + 50 * MB;
  char* A1p = base + 82 * MB;
  char* A2p = base + 114 * MB;
  char* A3p = base + 146 * MB;
  char* A4p = base + 178 * MB;
  char* A5p = base + 210 * MB;
  if (ws_size < 242 * MB) return;  // tripwire: failure signature absmax ~= ref absmax

  // Phase A: LN + QKV projections (plane GEMMs)
  bf16* xln_h = (bf16*)A0p;                  // 16MB [T][D]
  bf16* xln_l = (bf16*)(A0p + 16 * MB);      // 16MB
  bf16* wtqkv = (bf16*)A1p;                  // 48MB: 3x (hi 8MB + lo 8MB), A1..A2
  float* qb = (float*)A3p;                   // 3x 32MB fp32 contiguous (qb,kb,vb)
  float* kb = (float*)A4p;
  // Phase B: per-head projections + attention
  bf16* qab_h = (bf16*)A1p;                  // z-strided planes: qab (A1), kcb (A1+16MB)
  bf16* qab_l = (bf16*)(A1p + 8 * MB);
  bf16* kcb_h = (bf16*)(A1p + 16 * MB);
  bf16* kcb_l = (bf16*)(A1p + 24 * MB);
  float* vcb = (float*)A2p;                  // 16MB fp32 [TH][64]
  bf16* vct_h = (bf16*)(A2p + 16 * MB);      // 8MB [BH][64][S]
  bf16* vct_l = (bf16*)(A2p + 24 * MB);
  float* qgate = (float*)A0p;                // 32MB fp32 [TH][128]
  float* attc = (float*)A3p;                 // 16MB fp32 [TH][64]
  bf16* wto_h = (bf16*)(A3p + 16 * MB);      // 8MB
  bf16* wto_l = (bf16*)(A3p + 24 * MB);
  bf16* gated_h = (bf16*)A5p;                // 16MB [T][D]
  bf16* gated_l = (bf16*)(A5p + 16 * MB);
  // Phase C: MoE
  bf16* xf = (bf16*)A1p;
  bf16* s1 = (bf16*)(A1p + 16 * MB);
  bf16* wts1 = (bf16*)A2p;                   // 3x 8MB contiguous (s1, s3, s2)
  bf16* wts3 = (bf16*)(A2p + 8 * MB);
  bf16* wts2 = (bf16*)(A2p + 16 * MB);
  bf16* s3 = (bf16*)A3p;
  bf16* wteB_mid = (bf16*)A2p;               // 64MB: A2+A3 (s3 dead by then)
  bf16* wteB_out = (bf16*)A1p;               // 64MB: A1+A2 (xf/s1 dead by then)
  bf16* mid1 = (bf16*)A4p;
  bf16* mid3 = (bf16*)A5p;
  bf16* midg = (bf16*)A0p;
  bf16* eout = (bf16*)A3p;

  hipMemsetAsync(count, 0, 256, stream);

  dim3 tb(32, 8);
  // Batched weight transposes.
  k_transpose_split3<<<dim3(64, 64, 3), tb, 0, stream>>>(Wq, Wk, Wv, wtqkv);
  k_transpose32b3<<<dim3(2, 4, 3), tb, 0, stream>>>(Wqa, Wkc, Wvc, wtqa32);
  k_transpose32<<<dim3(4, 4, 1), tb, 0, stream>>>(Wqg, wtqg32, 128, 128);
  k_transpose32<<<dim3(4, 2, 1), tb, 0, stream>>>(Wov, wtov32, 64, 128);

  k_ln32_split<<<T_, 256, 0, stream>>>(hidden, ln1w, ln1b, xln_h, xln_l);

  // QKV projections fused (z=3), bit-identical to three k_gemm32s<0> launches.
  k_gemm32s_qkv<<<dim3(16, 32, 3), 256, 0, stream>>>(xln_h, xln_l, wtqkv, qb);

  k_rope32<<<8192, 256, 0, stream>>>(qb, kb);

  // Per-head projections fused (z=3): qab/kcb plane outputs, vcb fp32.
  k_projn64<<<dim3(1, 512, 3), 256, 0, stream>>>(qb, wtqa32, qab_h, vcb);
  k_gemm32<0><<<dim3(1, 512, 1), 256, 0, stream>>>(qb, 128, wtqg32, 128, qgate, 128, TH_, 128, 128, nullptr, nullptr);

  k_tr_v32s<<<dim3(64, 2, 32), tb, 0, stream>>>(vcb, vct_h, vct_l);
  k_transpose_split<<<dim3(64, 64, 1), tb, 0, stream>>>(Wo, wto_h, wto_l, 2048, 2048);  // qb dead now

  k_attn32p<<<dim3(16, 32, 1), 256, 0, stream>>>(qab_h, qab_l, kcb_h, kcb_l, vct_h, vct_l, attc);

  // bf16 shared-expert weights (A2 free after attention consumed vct)
  k_transpose_sh3<<<dim3(64, 64, 3), tb, 0, stream>>>(Ws1, Ws3, Ws2, wts1);

  // Uplift GEMM with fused silu-gate epilogue: gated = silu(qgate) * (attc@Wov^T),
  // split-stored directly (bit-identical to the old uplift+silu32_split pair).
  k_gemm32<3><<<dim3(1, 512, 1), 256, 0, stream>>>(attc, 64, wtov32, 64, qgate, 128, TH_, 128, 64, gated_h, gated_l);
  k_gemm32s<1><<<dim3(16, 32, 1), 256, 0, stream>>>(gated_h, gated_l, 2048, wto_h, wto_l, 2048, hbuf, 2048, T_, 2048, 2048, hidden);

  k_router<<<T_, 256, 0, stream>>>(hbuf, ln2w, ln2b, Wg, xf, count, permg, permt, wslot);

  // Shared-expert up projections fused (z=2), bit-identical per-output math.
  k_gemm_sh<<<dim3(16, 32, 2), 256, 0, stream>>>(xf, wts1, wts3, s1, s3);
  k_silu_mul<<<4096, 256, 0, stream>>>(s1, s3, s1, (long)T_ * 2048);  // smid in-place
  k_gemm<false><<<dim3(16, 32, 1), 256, 0, stream>>>(s1, 2048, wts2, 2048, shr, 2048, T_, 2048, 2048, nullptr, nullptr, nullptr);

  // Routed experts, fused: 4 experts x {We1, We3} per launch (z=8; wteB spans A2+A3).
  for (int p = 0; p < 2; p++) {
    k_transpose_moe<0><<<dim3(64, 64, 8), tb, 0, stream>>>(We1, We3, wteB_mid, 4 * p);
    k_gemm_moe<0><<<dim3(16, 32, 8), 256, 0, stream>>>(xf, 2048, wteB_mid, mid1, mid3, 2048, 2048, 2048, permt, permg, count, 4 * p);
  }
  k_silu_mul<<<8192, 256, 0, stream>>>(mid1, mid3, midg, (long)2 * T_ * 2048);
  // Down-projection: all 8 experts in one launch (z=8; wteB spans A1+A2).
  k_transpose_moe<1><<<dim3(64, 64, 8), tb, 0, stream>>>(We2, nullptr, wteB_out, 0);
  k_gemm_moe<1><<<dim3(16, 32, 8), 256, 0, stream>>>(midg, 2048, wteB_out, eout, nullptr, 2048, 2048, 2048, permt, permg, count, 0);

  k_combine<<<8192, 256, 0, stream>>>(hbuf, shr, eout, wslot, out);
}